// Round 1
// baseline (1133.589 us; speedup 1.0000x reference)
//
#include <hip/hip_runtime.h>
#include <stdint.h>

#define B_DIM 4
#define T_DIM 2048
#define C_DIM 2048
#define NH 16
#define HD 128

typedef unsigned short u16;
typedef __attribute__((ext_vector_type(8))) short short8;
typedef __attribute__((ext_vector_type(8))) u16 ushort8;
typedef __attribute__((ext_vector_type(4))) float f32x4;

__device__ __forceinline__ u16 f2bf(float f) {
  uint32_t u = __builtin_bit_cast(uint32_t, f);
  u = (u + 0x7FFFu + ((u >> 16) & 1u)) >> 16;
  return (u16)u;
}

__device__ __forceinline__ void gload16(const void* g, void* l) {
  __builtin_amdgcn_global_load_lds(
      (const __attribute__((address_space(1))) void*)g,
      (__attribute__((address_space(3))) void*)l, 16, 0, 0);
}

// ---------------- cast f32 -> bf16, 8 elems/thread ----------------
__global__ void cast_bf16_kernel(const float* __restrict__ src, u16* __restrict__ dst, int n) {
  int i = (blockIdx.x * 256 + threadIdx.x) * 8;
  if (i >= n) return;
  f32x4 a = *(const f32x4*)(src + i);
  f32x4 b = *(const f32x4*)(src + i + 4);
  ushort8 o;
  o[0] = f2bf(a[0]); o[1] = f2bf(a[1]); o[2] = f2bf(a[2]); o[3] = f2bf(a[3]);
  o[4] = f2bf(b[0]); o[5] = f2bf(b[1]); o[6] = f2bf(b[2]); o[7] = f2bf(b[3]);
  *(ushort8*)(dst + i) = o;
}

// ---------------- NT GEMM: C[m,n] = sum_k A[m,k] * B[n,k] ----------------
// A: [M,K] bf16 row-major, B: [N,K] bf16 row-major. 128x128 tile, BK=32,
// 4 waves (2x2), each wave 64x64 (4x4 16x16 frags). Double-buffered LDS via
// global_load_lds width-16.
template<bool OUT_F32>
__global__ __launch_bounds__(256)
void gemm_bt(const u16* __restrict__ A, const u16* __restrict__ Bw,
             void* __restrict__ Cout, int M, int N, int K) {
  __shared__ __align__(16) u16 Alds[2][128 * 32];
  __shared__ __align__(16) u16 Blds[2][128 * 32];
  const int nbn = N >> 7;
  const int bm = (blockIdx.x / nbn) << 7;
  const int bn = (blockIdx.x % nbn) << 7;
  const int tid = threadIdx.x;
  const int wid = tid >> 6, lane = tid & 63;
  const int wr = wid >> 1, wc = wid & 1;

  // staging addresses: wave w covers rows w*32 .. w*32+31 (2 issues of 16 rows)
  const int srow = wid * 32 + (lane >> 2);
  const int skel = (lane & 3) * 8;
  const u16* Ag = A + (size_t)(bm + srow) * K + skel;
  const u16* Bg = Bw + (size_t)(bn + srow) * K + skel;
  u16* AldsW = &Alds[0][0] + wid * 1024;   // wave-uniform LDS dest base
  u16* BldsW = &Blds[0][0] + wid * 1024;

  f32x4 zero4 = {0.f, 0.f, 0.f, 0.f};
  f32x4 acc[4][4];
#pragma unroll
  for (int i = 0; i < 4; ++i)
#pragma unroll
    for (int j = 0; j < 4; ++j) acc[i][j] = zero4;

  const int nk = K >> 5;
  // prologue: stage buffer 0 for kt=0
  gload16(Ag, AldsW);            gload16(Ag + 16 * (size_t)K, AldsW + 512);
  gload16(Bg, BldsW);            gload16(Bg + 16 * (size_t)K, BldsW + 512);
  __syncthreads();

  const int ro = (lane & 15) * 32 + (lane >> 4) * 8;
  for (int kt = 0; kt < nk; ++kt) {
    const int cur = kt & 1;
    if (kt + 1 < nk) {
      const u16* a = Ag + (size_t)(kt + 1) * 32;
      const u16* b = Bg + (size_t)(kt + 1) * 32;
      u16* ad = AldsW + (cur ^ 1) * 4096;
      u16* bd = BldsW + (cur ^ 1) * 4096;
      gload16(a, ad);            gload16(a + 16 * (size_t)K, ad + 512);
      gload16(b, bd);            gload16(b + 16 * (size_t)K, bd + 512);
    }
    const u16* Ab = &Alds[cur][0];
    const u16* Bb = &Blds[cur][0];
    short8 af[4], bf[4];
#pragma unroll
    for (int i = 0; i < 4; ++i) {
      af[i] = *(const short8*)(Ab + (wr * 64 + i * 16) * 32 + ro);
      bf[i] = *(const short8*)(Bb + (wc * 64 + i * 16) * 32 + ro);
    }
#pragma unroll
    for (int mi = 0; mi < 4; ++mi)
#pragma unroll
      for (int ni = 0; ni < 4; ++ni)
        acc[mi][ni] = __builtin_amdgcn_mfma_f32_16x16x32_bf16(af[mi], bf[ni], acc[mi][ni], 0, 0, 0);
    __syncthreads();   // drains vmcnt (stage done) + lgkm; protects buffer reuse
  }

  // epilogue: D layout row=(l>>4)*4+r, col=l&15
  const int orow = wr * 64 + (lane >> 4) * 4;
  const int ocol = wc * 64 + (lane & 15);
#pragma unroll
  for (int mi = 0; mi < 4; ++mi)
#pragma unroll
    for (int ni = 0; ni < 4; ++ni) {
      f32x4 v = acc[mi][ni];
      size_t base = (size_t)(bm + orow + mi * 16) * N + (bn + ocol + ni * 16);
      if (OUT_F32) {
        float* C = (float*)Cout;
#pragma unroll
        for (int r = 0; r < 4; ++r) C[base + (size_t)r * N] = v[r];
      } else {
        u16* C = (u16*)Cout;
#pragma unroll
        for (int r = 0; r < 4; ++r) C[base + (size_t)r * N] = f2bf(v[r]);
      }
    }
}

// ---------------- causal flash attention ----------------
// grid (T/64, B*H), 256 threads. Each wave: 16 q-rows. KV tile = 64 rows.
__global__ __launch_bounds__(256)
void attn_kernel(const u16* __restrict__ Qg, const u16* __restrict__ Kg,
                 const u16* __restrict__ Vg, u16* __restrict__ Y) {
  __shared__ __align__(16) u16 Klds[64][136];   // K tile, +8 pad
  __shared__ __align__(16) u16 Vt[128][72];     // V^T tile, +8 pad
  __shared__ __align__(16) u16 Plds[4][16][72]; // per-wave P
  const int qb = blockIdx.x * 64;
  const int bh = blockIdx.y;
  const int b = bh >> 4, h = bh & 15;
  const size_t base = (size_t)b * T_DIM * C_DIM + (size_t)h * HD;
  const int tid = threadIdx.x, wid = tid >> 6, lane = tid & 63;
  const float scale = 0.08838834764831845f;

  // Q fragments for this wave's 16 rows (held for whole kernel)
  short8 qf[4];
  {
    const u16* qp = Qg + base + (size_t)(qb + wid * 16 + (lane & 15)) * C_DIM + (lane >> 4) * 8;
#pragma unroll
    for (int dc = 0; dc < 4; ++dc) qf[dc] = *(const short8*)(qp + dc * 32);
  }

  f32x4 zero4 = {0.f, 0.f, 0.f, 0.f};
  f32x4 ao[8];
#pragma unroll
  for (int i = 0; i < 8; ++i) ao[i] = zero4;
  float m_run[4] = {-1e30f, -1e30f, -1e30f, -1e30f};
  float l_run[4] = {0.f, 0.f, 0.f, 0.f};

  const int srow = tid >> 4;       // 0..15
  const int sd = (tid & 15) * 8;   // 0..120

  for (int kb = 0; kb <= qb; kb += 64) {
    // stage K tile (straight) and V tile (transposed)
#pragma unroll
    for (int it = 0; it < 4; ++it) {
      const int j = it * 16 + srow;
      *(ushort8*)&Klds[j][sd] = *(const ushort8*)(Kg + base + (size_t)(kb + j) * C_DIM + sd);
      ushort8 vv = *(const ushort8*)(Vg + base + (size_t)(kb + j) * C_DIM + sd);
#pragma unroll
      for (int jj = 0; jj < 8; ++jj) Vt[sd + jj][j] = vv[jj];
    }
    __syncthreads();

    // S = Q K^T  (16 x 64 per wave)
    f32x4 s[4];
#pragma unroll
    for (int jt = 0; jt < 4; ++jt) {
      f32x4 a = zero4;
#pragma unroll
      for (int dc = 0; dc < 4; ++dc) {
        short8 kf = *(const short8*)&Klds[jt * 16 + (lane & 15)][dc * 32 + (lane >> 4) * 8];
        a = __builtin_amdgcn_mfma_f32_16x16x32_bf16(qf[dc], kf, a, 0, 0, 0);
      }
      s[jt] = a;
    }

    // scale + causal mask (only diagonal tile needs it)
    const bool diag = (kb == qb);
    const int qr0 = qb + wid * 16 + (lane >> 4) * 4;
#pragma unroll
    for (int jt = 0; jt < 4; ++jt) {
      const int kcol = kb + jt * 16 + (lane & 15);
#pragma unroll
      for (int r = 0; r < 4; ++r) {
        float sv = s[jt][r] * scale;
        if (diag && (kcol > qr0 + r)) sv = -1e30f;
        s[jt][r] = sv;
      }
    }

    // row max over 16 lanes (cols)
    float mx[4];
#pragma unroll
    for (int r = 0; r < 4; ++r)
      mx[r] = fmaxf(fmaxf(s[0][r], s[1][r]), fmaxf(s[2][r], s[3][r]));
#pragma unroll
    for (int off = 1; off < 16; off <<= 1)
#pragma unroll
      for (int r = 0; r < 4; ++r) mx[r] = fmaxf(mx[r], __shfl_xor(mx[r], off, 64));

    float mn[4], corr[4];
#pragma unroll
    for (int r = 0; r < 4; ++r) {
      mn[r] = fmaxf(m_run[r], mx[r]);
      corr[r] = __expf(m_run[r] - mn[r]);
      m_run[r] = mn[r];
    }

    // P = exp(s - mn); row sums
    float sm[4] = {0.f, 0.f, 0.f, 0.f};
#pragma unroll
    for (int jt = 0; jt < 4; ++jt)
#pragma unroll
      for (int r = 0; r < 4; ++r) {
        float p = __expf(s[jt][r] - mn[r]);
        s[jt][r] = p;
        sm[r] += p;
      }
#pragma unroll
    for (int off = 1; off < 16; off <<= 1)
#pragma unroll
      for (int r = 0; r < 4; ++r) sm[r] += __shfl_xor(sm[r], off, 64);
#pragma unroll
    for (int r = 0; r < 4; ++r) l_run[r] = l_run[r] * corr[r] + sm[r];

    // write P (bf16) to per-wave LDS in row-major [16][64]
#pragma unroll
    for (int jt = 0; jt < 4; ++jt)
#pragma unroll
      for (int r = 0; r < 4; ++r)
        Plds[wid][(lane >> 4) * 4 + r][jt * 16 + (lane & 15)] = f2bf(s[jt][r]);

    // rescale O
#pragma unroll
    for (int dc = 0; dc < 8; ++dc)
#pragma unroll
      for (int r = 0; r < 4; ++r) ao[dc][r] *= corr[r];

    // O += P @ V  (A = P 16x64, B = V 64x128 via Vt)
#pragma unroll
    for (int dc = 0; dc < 8; ++dc) {
#pragma unroll
      for (int kc = 0; kc < 2; ++kc) {
        short8 pf = *(const short8*)&Plds[wid][lane & 15][kc * 32 + (lane >> 4) * 8];
        short8 vf = *(const short8*)&Vt[dc * 16 + (lane & 15)][kc * 32 + (lane >> 4) * 8];
        ao[dc] = __builtin_amdgcn_mfma_f32_16x16x32_bf16(pf, vf, ao[dc], 0, 0, 0);
      }
    }
    __syncthreads();   // before next tile overwrites Klds/Vt
  }

  // normalize + write y (bf16), same [B*T][H*HD] layout as inputs
  float rcp[4];
#pragma unroll
  for (int r = 0; r < 4; ++r) rcp[r] = 1.0f / l_run[r];
  u16* yp = Y + base + (size_t)(qb + wid * 16 + (lane >> 4) * 4) * C_DIM + (lane & 15);
#pragma unroll
  for (int dc = 0; dc < 8; ++dc)
#pragma unroll
    for (int r = 0; r < 4; ++r)
      yp[(size_t)r * C_DIM + dc * 16] = f2bf(ao[dc][r] * rcp[r]);
}

extern "C" void kernel_launch(void* const* d_in, const int* in_sizes, int n_in,
                              void* d_out, int out_size, void* d_ws, size_t ws_size,
                              hipStream_t stream) {
  const float* x  = (const float*)d_in[0];
  const float* Wq = (const float*)d_in[1];
  const float* Wk = (const float*)d_in[2];
  const float* Wv = (const float*)d_in[3];
  const float* Wo = (const float*)d_in[4];
  float* out = (float*)d_out;

  const size_t SZX = (size_t)8192 * 2048;   // x / q / k / v / y elements
  const size_t SZW = (size_t)2048 * 2048;   // weight elements
  u16* xb  = (u16*)d_ws;
  u16* Wqb = xb + SZX;
  u16* Wkb = Wqb + SZW;
  u16* Wvb = Wkb + SZW;
  u16* Wob = Wvb + SZW;
  u16* Qb  = Wob + SZW;   // Q, later reused as Y (provably disjoint per-block R->W)
  u16* Kb  = Qb + SZX;
  u16* Vb  = Kb + SZX;
  // total ws usage: 160 MB

  cast_bf16_kernel<<<(int)(SZX / 2048), 256, 0, stream>>>(x,  xb,  (int)SZX);
  cast_bf16_kernel<<<(int)(SZW / 2048), 256, 0, stream>>>(Wq, Wqb, (int)SZW);
  cast_bf16_kernel<<<(int)(SZW / 2048), 256, 0, stream>>>(Wk, Wkb, (int)SZW);
  cast_bf16_kernel<<<(int)(SZW / 2048), 256, 0, stream>>>(Wv, Wvb, (int)SZW);
  cast_bf16_kernel<<<(int)(SZW / 2048), 256, 0, stream>>>(Wo, Wob, (int)SZW);

  gemm_bt<false><<<1024, 256, 0, stream>>>(xb, Wqb, Qb, 8192, 2048, 2048);
  gemm_bt<false><<<1024, 256, 0, stream>>>(xb, Wkb, Kb, 8192, 2048, 2048);
  gemm_bt<false><<<1024, 256, 0, stream>>>(xb, Wvb, Vb, 8192, 2048, 2048);

  attn_kernel<<<dim3(T_DIM / 64, B_DIM * NH), 256, 0, stream>>>(Qb, Kb, Vb, Qb);

  gemm_bt<true><<<1024, 256, 0, stream>>>(Qb, Wob, out, 8192, 2048, 2048);
}

// Round 3
// 701.694 us; speedup vs baseline: 1.6155x; 1.6155x over previous
//
#include <hip/hip_runtime.h>
#include <stdint.h>

#define B_DIM 4
#define T_DIM 2048
#define C_DIM 2048
#define NH 16
#define HD 128

typedef unsigned short u16;
typedef __attribute__((ext_vector_type(8))) short short8;
typedef __attribute__((ext_vector_type(8))) u16 ushort8;
typedef __attribute__((ext_vector_type(4))) u16 u16x4;
typedef __attribute__((ext_vector_type(4))) float f32x4;

__device__ __forceinline__ u16 f2bf(float f) {
  uint32_t u = __builtin_bit_cast(uint32_t, f);
  u = (u + 0x7FFFu + ((u >> 16) & 1u)) >> 16;
  return (u16)u;
}

__device__ __forceinline__ void gload16(const void* g, void* l) {
  __builtin_amdgcn_global_load_lds(
      (const __attribute__((address_space(1))) void*)g,
      (__attribute__((address_space(3))) void*)l, 16, 0, 0);
}

// ---------------- cast f32 -> bf16, 8 elems/thread ----------------
__global__ void cast_bf16_kernel(const float* __restrict__ src, u16* __restrict__ dst, int n) {
  int i = (blockIdx.x * 256 + threadIdx.x) * 8;
  if (i >= n) return;
  f32x4 a = *(const f32x4*)(src + i);
  f32x4 b = *(const f32x4*)(src + i + 4);
  ushort8 o;
  o[0] = f2bf(a[0]); o[1] = f2bf(a[1]); o[2] = f2bf(a[2]); o[3] = f2bf(a[3]);
  o[4] = f2bf(b[0]); o[5] = f2bf(b[1]); o[6] = f2bf(b[2]); o[7] = f2bf(b[3]);
  *(ushort8*)(dst + i) = o;
}

// ---------------- NT GEMM: C[m,n] = sum_k A[m,k] * B[n,k] ----------------
// MODE 0: bf16 row-major out. MODE 1: f32 row-major out.
// MODE 2: bf16 out transposed per batch: C_t[b][n][t] = C[m=b*2048+t][n]
//         (flat offset b*2048*2048 + n*2048 + t) -- used for V so attention
//         can stage V^T tiles without an in-kernel transpose.
template<int MODE>
__global__ __launch_bounds__(256)
void gemm_bt(const u16* __restrict__ A, const u16* __restrict__ Bw,
             void* __restrict__ Cout, int M, int N, int K) {
  __shared__ __align__(16) u16 Alds[2][128 * 32];
  __shared__ __align__(16) u16 Blds[2][128 * 32];
  const int nbn = N >> 7;
  const int bm = (blockIdx.x / nbn) << 7;
  const int bn = (blockIdx.x % nbn) << 7;
  const int tid = threadIdx.x;
  const int wid = tid >> 6, lane = tid & 63;
  const int wr = wid >> 1, wc = wid & 1;

  const int srow = wid * 32 + (lane >> 2);
  const int skel = (lane & 3) * 8;
  const u16* Ag = A + (size_t)(bm + srow) * K + skel;
  const u16* Bg = Bw + (size_t)(bn + srow) * K + skel;
  u16* AldsW = &Alds[0][0] + wid * 1024;
  u16* BldsW = &Blds[0][0] + wid * 1024;

  f32x4 zero4 = {0.f, 0.f, 0.f, 0.f};
  f32x4 acc[4][4];
#pragma unroll
  for (int i = 0; i < 4; ++i)
#pragma unroll
    for (int j = 0; j < 4; ++j) acc[i][j] = zero4;

  const int nk = K >> 5;
  gload16(Ag, AldsW);            gload16(Ag + 16 * (size_t)K, AldsW + 512);
  gload16(Bg, BldsW);            gload16(Bg + 16 * (size_t)K, BldsW + 512);
  __syncthreads();

  const int ro = (lane & 15) * 32 + (lane >> 4) * 8;
  for (int kt = 0; kt < nk; ++kt) {
    const int cur = kt & 1;
    if (kt + 1 < nk) {
      const u16* a = Ag + (size_t)(kt + 1) * 32;
      const u16* b = Bg + (size_t)(kt + 1) * 32;
      u16* ad = AldsW + (cur ^ 1) * 4096;
      u16* bd = BldsW + (cur ^ 1) * 4096;
      gload16(a, ad);            gload16(a + 16 * (size_t)K, ad + 512);
      gload16(b, bd);            gload16(b + 16 * (size_t)K, bd + 512);
    }
    const u16* Ab = &Alds[cur][0];
    const u16* Bb = &Blds[cur][0];
    short8 af[4], bf[4];
#pragma unroll
    for (int i = 0; i < 4; ++i) {
      af[i] = *(const short8*)(Ab + (wr * 64 + i * 16) * 32 + ro);
      bf[i] = *(const short8*)(Bb + (wc * 64 + i * 16) * 32 + ro);
    }
    __builtin_amdgcn_s_setprio(1);
#pragma unroll
    for (int mi = 0; mi < 4; ++mi)
#pragma unroll
      for (int ni = 0; ni < 4; ++ni)
        acc[mi][ni] = __builtin_amdgcn_mfma_f32_16x16x32_bf16(af[mi], bf[ni], acc[mi][ni], 0, 0, 0);
    __builtin_amdgcn_s_setprio(0);
    __syncthreads();
  }

  // D layout: row=(l>>4)*4+r, col=l&15
  const int orow = wr * 64 + (lane >> 4) * 4;
  const int ocol = wc * 64 + (lane & 15);
#pragma unroll
  for (int mi = 0; mi < 4; ++mi)
#pragma unroll
    for (int ni = 0; ni < 4; ++ni) {
      f32x4 v = acc[mi][ni];
      if (MODE == 2) {
        u16* C = (u16*)Cout;
        size_t base = (size_t)(bm >> 11) * ((size_t)T_DIM * C_DIM) +
                      (size_t)(bn + ocol + ni * 16) * T_DIM +
                      (size_t)((bm & 2047) + orow + mi * 16);
        u16x4 o;
        o[0] = f2bf(v[0]); o[1] = f2bf(v[1]); o[2] = f2bf(v[2]); o[3] = f2bf(v[3]);
        *(u16x4*)&C[base] = o;
      } else {
        size_t base = (size_t)(bm + orow + mi * 16) * N + (bn + ocol + ni * 16);
        if (MODE == 1) {
          float* C = (float*)Cout;
#pragma unroll
          for (int r = 0; r < 4; ++r) C[base + (size_t)r * N] = v[r];
        } else {
          u16* C = (u16*)Cout;
#pragma unroll
          for (int r = 0; r < 4; ++r) C[base + (size_t)r * N] = f2bf(v[r]);
        }
      }
    }
}

// ---------------- causal flash attention ----------------
// grid (T/128, B*H), 512 threads = 8 waves, 16 q-rows per wave. KV tile = 64.
// K tile staged row-major [64][128+pad]; V staged from the pre-transposed
// global V^T (layout [b][n][t]) as [128 d][64 t + pad] -> PV B-fragments are
// contiguous ds_read_b128, no transpose scatter.
__global__ __launch_bounds__(512)
void attn_kernel(const u16* __restrict__ Qg, const u16* __restrict__ Kg,
                 const u16* __restrict__ VtG, u16* __restrict__ Y) {
  __shared__ __align__(16) u16 Klds[64][136];
  __shared__ __align__(16) u16 Vlds[128][72];
  __shared__ __align__(16) u16 Plds[8][16][72];
  const int qb = blockIdx.x * 128;
  const int bh = blockIdx.y;
  const int b = bh >> 4, h = bh & 15;
  const size_t qkbase = (size_t)b * T_DIM * C_DIM + (size_t)h * HD;
  const size_t vtbase = (size_t)b * T_DIM * C_DIM + (size_t)h * HD * T_DIM;
  const int tid = threadIdx.x, wid = tid >> 6, lane = tid & 63;
  const float scale2 = 0.08838834764831845f * 1.4426950408889634f;  // scale*log2(e)

  // Q fragments: wave's 16 rows, held in regs for the whole kernel
  short8 qf[4];
  {
    const u16* qp = Qg + qkbase + (size_t)(qb + wid * 16 + (lane & 15)) * C_DIM + (lane >> 4) * 8;
#pragma unroll
    for (int dc = 0; dc < 4; ++dc) qf[dc] = *(const short8*)(qp + dc * 32);
  }

  f32x4 zero4 = {0.f, 0.f, 0.f, 0.f};
  f32x4 ao[8];
#pragma unroll
  for (int i = 0; i < 8; ++i) ao[i] = zero4;
  float m_run[4] = {-1e30f, -1e30f, -1e30f, -1e30f};
  float l_run[4] = {0.f, 0.f, 0.f, 0.f};

  // staging: K 64x128 (2 ushort8/thread), V^T 128x64 (2 ushort8/thread)
  const int kr = tid >> 4, kc = (tid & 15) * 8;
  const int vr = tid >> 3, vc = (tid & 7) * 8;
  const u16* Kgp = Kg + qkbase + (size_t)kr * C_DIM + kc;
  const u16* Vgp = VtG + vtbase + (size_t)vr * T_DIM + vc;

  const int nt = (qb >> 6) + 2;
  const int myrow_lo = qb + wid * 16;
  const int qr0 = myrow_lo + (lane >> 4) * 4;

  for (int t = 0; t < nt; ++t) {
    const int kb = t * 64;
    *(ushort8*)&Klds[kr][kc]       = *(const ushort8*)(Kgp + (size_t)kb * C_DIM);
    *(ushort8*)&Klds[kr + 32][kc]  = *(const ushort8*)(Kgp + (size_t)(kb + 32) * C_DIM);
    *(ushort8*)&Vlds[vr][vc]       = *(const ushort8*)(Vgp + kb);
    *(ushort8*)&Vlds[vr + 64][vc]  = *(const ushort8*)(Vgp + (size_t)64 * T_DIM + kb);
    __syncthreads();

    if (kb <= myrow_lo + 15) {   // wave has at least one unmasked column
      // S = Q K^T (16 x 64)
      f32x4 s[4];
      __builtin_amdgcn_s_setprio(1);
#pragma unroll
      for (int jt = 0; jt < 4; ++jt) {
        f32x4 a = zero4;
#pragma unroll
        for (int dc = 0; dc < 4; ++dc) {
          short8 kf = *(const short8*)&Klds[jt * 16 + (lane & 15)][dc * 32 + (lane >> 4) * 8];
          a = __builtin_amdgcn_mfma_f32_16x16x32_bf16(qf[dc], kf, a, 0, 0, 0);
        }
        s[jt] = a;
      }
      __builtin_amdgcn_s_setprio(0);

      // scale (log2 domain) + causal mask
      const bool domask = (kb + 63) > myrow_lo;
#pragma unroll
      for (int jt = 0; jt < 4; ++jt) {
        const int kcol = kb + jt * 16 + (lane & 15);
#pragma unroll
        for (int r = 0; r < 4; ++r) {
          float sv = s[jt][r] * scale2;
          if (domask && (kcol > qr0 + r)) sv = -1e30f;
          s[jt][r] = sv;
        }
      }

      // row max over the 16 lanes of the row group
      float mx[4];
#pragma unroll
      for (int r = 0; r < 4; ++r)
        mx[r] = fmaxf(fmaxf(s[0][r], s[1][r]), fmaxf(s[2][r], s[3][r]));
#pragma unroll
      for (int off = 1; off < 16; off <<= 1)
#pragma unroll
        for (int r = 0; r < 4; ++r) mx[r] = fmaxf(mx[r], __shfl_xor(mx[r], off, 64));

      float mn[4], corr[4];
#pragma unroll
      for (int r = 0; r < 4; ++r) {
        mn[r] = fmaxf(m_run[r], mx[r]);
        corr[r] = __builtin_amdgcn_exp2f(m_run[r] - mn[r]);
        m_run[r] = mn[r];
      }

      float sm[4] = {0.f, 0.f, 0.f, 0.f};
#pragma unroll
      for (int jt = 0; jt < 4; ++jt)
#pragma unroll
        for (int r = 0; r < 4; ++r) {
          float p = __builtin_amdgcn_exp2f(s[jt][r] - mn[r]);
          s[jt][r] = p;
          sm[r] += p;
        }
#pragma unroll
      for (int off = 1; off < 16; off <<= 1)
#pragma unroll
        for (int r = 0; r < 4; ++r) sm[r] += __shfl_xor(sm[r], off, 64);
#pragma unroll
      for (int r = 0; r < 4; ++r) l_run[r] = l_run[r] * corr[r] + sm[r];

      // P -> per-wave LDS (A-fragment layout for PV)
#pragma unroll
      for (int jt = 0; jt < 4; ++jt)
#pragma unroll
        for (int r = 0; r < 4; ++r)
          Plds[wid][(lane >> 4) * 4 + r][jt * 16 + (lane & 15)] = f2bf(s[jt][r]);

      // rescale O
#pragma unroll
      for (int dc = 0; dc < 8; ++dc)
#pragma unroll
        for (int r = 0; r < 4; ++r) ao[dc][r] *= corr[r];

      // O += P @ V
      __builtin_amdgcn_s_setprio(1);
#pragma unroll
      for (int dc = 0; dc < 8; ++dc) {
#pragma unroll
        for (int kc2 = 0; kc2 < 2; ++kc2) {
          short8 pf = *(const short8*)&Plds[wid][lane & 15][kc2 * 32 + (lane >> 4) * 8];
          short8 vf = *(const short8*)&Vlds[dc * 16 + (lane & 15)][kc2 * 32 + (lane >> 4) * 8];
          ao[dc] = __builtin_amdgcn_mfma_f32_16x16x32_bf16(pf, vf, ao[dc], 0, 0, 0);
        }
      }
      __builtin_amdgcn_s_setprio(0);
    }
    __syncthreads();
  }

  float rcp[4];
#pragma unroll
  for (int r = 0; r < 4; ++r) rcp[r] = 1.0f / l_run[r];
  u16* yp = Y + qkbase + (size_t)(qb + wid * 16 + (lane >> 4) * 4) * C_DIM + (lane & 15);
#pragma unroll
  for (int dc = 0; dc < 8; ++dc)
#pragma unroll
    for (int r = 0; r < 4; ++r)
      yp[(size_t)r * C_DIM + dc * 16] = f2bf(ao[dc][r] * rcp[r]);
}

extern "C" void kernel_launch(void* const* d_in, const int* in_sizes, int n_in,
                              void* d_out, int out_size, void* d_ws, size_t ws_size,
                              hipStream_t stream) {
  const float* x  = (const float*)d_in[0];
  const float* Wq = (const float*)d_in[1];
  const float* Wk = (const float*)d_in[2];
  const float* Wv = (const float*)d_in[3];
  const float* Wo = (const float*)d_in[4];
  float* out = (float*)d_out;

  const size_t SZX = (size_t)8192 * 2048;
  const size_t SZW = (size_t)2048 * 2048;
  u16* xb  = (u16*)d_ws;
  u16* Wqb = xb + SZX;
  u16* Wkb = Wqb + SZW;
  u16* Wvb = Wkb + SZW;
  u16* Wob = Wvb + SZW;
  u16* Qb  = Wob + SZW;   // Q, later overwritten in place by attention output Y
  u16* Kb  = Qb + SZX;
  u16* Vb  = Kb + SZX;    // holds V^T in [b][n][t] layout

  cast_bf16_kernel<<<(int)(SZX / 2048), 256, 0, stream>>>(x,  xb,  (int)SZX);
  cast_bf16_kernel<<<(int)(SZW / 2048), 256, 0, stream>>>(Wq, Wqb, (int)SZW);
  cast_bf16_kernel<<<(int)(SZW / 2048), 256, 0, stream>>>(Wk, Wkb, (int)SZW);
  cast_bf16_kernel<<<(int)(SZW / 2048), 256, 0, stream>>>(Wv, Wvb, (int)SZW);
  cast_bf16_kernel<<<(int)(SZW / 2048), 256, 0, stream>>>(Wo, Wob, (int)SZW);

  gemm_bt<0><<<1024, 256, 0, stream>>>(xb, Wqb, Qb, 8192, 2048, 2048);
  gemm_bt<0><<<1024, 256, 0, stream>>>(xb, Wkb, Kb, 8192, 2048, 2048);
  gemm_bt<2><<<1024, 256, 0, stream>>>(xb, Wvb, Vb, 8192, 2048, 2048);  // V^T out

  attn_kernel<<<dim3(T_DIM / 128, B_DIM * NH), 512, 0, stream>>>(Qb, Kb, Vb, Qb);

  gemm_bt<1><<<1024, 256, 0, stream>>>(Qb, Wob, out, 8192, 2048, 2048);
}

// Round 4
// 572.021 us; speedup vs baseline: 1.9817x; 1.2267x over previous
//
#include <hip/hip_runtime.h>
#include <stdint.h>

#define B_DIM 4
#define T_DIM 2048
#define C_DIM 2048
#define NH 16
#define HD 128

typedef unsigned short u16;
typedef __attribute__((ext_vector_type(8))) short short8;
typedef __attribute__((ext_vector_type(8))) u16 ushort8;
typedef __attribute__((ext_vector_type(4))) u16 u16x4;
typedef __attribute__((ext_vector_type(4))) float f32x4;

__device__ __forceinline__ u16 f2bf(float f) {
  uint32_t u = __builtin_bit_cast(uint32_t, f);
  u = (u + 0x7FFFu + ((u >> 16) & 1u)) >> 16;
  return (u16)u;
}

__device__ __forceinline__ void gload16(const void* g, void* l) {
  __builtin_amdgcn_global_load_lds(
      (const __attribute__((address_space(1))) void*)g,
      (__attribute__((address_space(3))) void*)l, 16, 0, 0);
}

// ---------------- cast f32 -> bf16, 8 elems/thread ----------------
__global__ void cast_bf16_kernel(const float* __restrict__ src, u16* __restrict__ dst, int n) {
  int i = (blockIdx.x * 256 + threadIdx.x) * 8;
  if (i >= n) return;
  f32x4 a = *(const f32x4*)(src + i);
  f32x4 b = *(const f32x4*)(src + i + 4);
  ushort8 o;
  o[0] = f2bf(a[0]); o[1] = f2bf(a[1]); o[2] = f2bf(a[2]); o[3] = f2bf(a[3]);
  o[4] = f2bf(b[0]); o[5] = f2bf(b[1]); o[6] = f2bf(b[2]); o[7] = f2bf(b[3]);
  *(ushort8*)(dst + i) = o;
}

// ---------------- NT GEMM: C[m,n] = sum_k A[m,k] * B[n,k] ----------------
// MODE 0: bf16 row-major out. MODE 1: f32 row-major out.
// MODE 2: bf16 out transposed per batch: C_t[b][n][t] = C[m=b*2048+t][n].
template<int MODE>
__global__ __launch_bounds__(256)
void gemm_bt(const u16* __restrict__ A, const u16* __restrict__ Bw,
             void* __restrict__ Cout, int M, int N, int K) {
  __shared__ __align__(16) u16 Alds[2][128 * 32];
  __shared__ __align__(16) u16 Blds[2][128 * 32];
  const int nbn = N >> 7;
  // XCD-aware swizzle (gridDim.x % 8 == 0): each XCD gets a contiguous chunk
  const int cpx = gridDim.x >> 3;
  const int swz = (blockIdx.x & 7) * cpx + (blockIdx.x >> 3);
  const int bm = (swz / nbn) << 7;
  const int bn = (swz % nbn) << 7;
  const int tid = threadIdx.x;
  const int wid = tid >> 6, lane = tid & 63;
  const int wr = wid >> 1, wc = wid & 1;

  const int srow = wid * 32 + (lane >> 2);
  const int skel = (lane & 3) * 8;
  const u16* Ag = A + (size_t)(bm + srow) * K + skel;
  const u16* Bg = Bw + (size_t)(bn + srow) * K + skel;
  u16* AldsW = &Alds[0][0] + wid * 1024;
  u16* BldsW = &Blds[0][0] + wid * 1024;

  f32x4 zero4 = {0.f, 0.f, 0.f, 0.f};
  f32x4 acc[4][4];
#pragma unroll
  for (int i = 0; i < 4; ++i)
#pragma unroll
    for (int j = 0; j < 4; ++j) acc[i][j] = zero4;

  const int nk = K >> 5;
  gload16(Ag, AldsW);            gload16(Ag + 16 * (size_t)K, AldsW + 512);
  gload16(Bg, BldsW);            gload16(Bg + 16 * (size_t)K, BldsW + 512);
  __syncthreads();

  const int ro = (lane & 15) * 32 + (lane >> 4) * 8;
  for (int kt = 0; kt < nk; ++kt) {
    const int cur = kt & 1;
    if (kt + 1 < nk) {
      const u16* a = Ag + (size_t)(kt + 1) * 32;
      const u16* b = Bg + (size_t)(kt + 1) * 32;
      u16* ad = AldsW + (cur ^ 1) * 4096;
      u16* bd = BldsW + (cur ^ 1) * 4096;
      gload16(a, ad);            gload16(a + 16 * (size_t)K, ad + 512);
      gload16(b, bd);            gload16(b + 16 * (size_t)K, bd + 512);
    }
    const u16* Ab = &Alds[cur][0];
    const u16* Bb = &Blds[cur][0];
    short8 af[4], bf[4];
#pragma unroll
    for (int i = 0; i < 4; ++i) {
      af[i] = *(const short8*)(Ab + (wr * 64 + i * 16) * 32 + ro);
      bf[i] = *(const short8*)(Bb + (wc * 64 + i * 16) * 32 + ro);
    }
    __builtin_amdgcn_s_setprio(1);
#pragma unroll
    for (int mi = 0; mi < 4; ++mi)
#pragma unroll
      for (int ni = 0; ni < 4; ++ni)
        acc[mi][ni] = __builtin_amdgcn_mfma_f32_16x16x32_bf16(af[mi], bf[ni], acc[mi][ni], 0, 0, 0);
    __builtin_amdgcn_s_setprio(0);
    __syncthreads();
  }

  // D layout: row=(l>>4)*4+r, col=l&15
  const int orow = wr * 64 + (lane >> 4) * 4;
  const int ocol = wc * 64 + (lane & 15);
#pragma unroll
  for (int mi = 0; mi < 4; ++mi)
#pragma unroll
    for (int ni = 0; ni < 4; ++ni) {
      f32x4 v = acc[mi][ni];
      if (MODE == 2) {
        u16* C = (u16*)Cout;
        size_t base = (size_t)(bm >> 11) * ((size_t)T_DIM * C_DIM) +
                      (size_t)(bn + ocol + ni * 16) * T_DIM +
                      (size_t)((bm & 2047) + orow + mi * 16);
        u16x4 o;
        o[0] = f2bf(v[0]); o[1] = f2bf(v[1]); o[2] = f2bf(v[2]); o[3] = f2bf(v[3]);
        *(u16x4*)&C[base] = o;
      } else {
        size_t base = (size_t)(bm + orow + mi * 16) * N + (bn + ocol + ni * 16);
        if (MODE == 1) {
          float* C = (float*)Cout;
#pragma unroll
          for (int r = 0; r < 4; ++r) C[base + (size_t)r * N] = v[r];
        } else {
          u16* C = (u16*)Cout;
#pragma unroll
          for (int r = 0; r < 4; ++r) C[base + (size_t)r * N] = f2bf(v[r]);
        }
      }
    }
}

// ---------------- causal flash attention ----------------
// grid (8, B*H), 512 threads. Block p processes q-blocks p and 15-p (128 rows
// each) sequentially -> 34 KV tiles per block, perfectly balanced.
// Async-STAGE: next tile's K/V global->regs issued under current compute.
__global__ __launch_bounds__(512)
void attn_kernel(const u16* __restrict__ Qg, const u16* __restrict__ Kg,
                 const u16* __restrict__ VtG, u16* __restrict__ Y) {
  __shared__ __align__(16) u16 Klds[64][136];
  __shared__ __align__(16) u16 Vlds[128][72];
  __shared__ __align__(16) u16 Plds[8][16][72];
  const int pair = blockIdx.x;
  const int bh = blockIdx.y;
  const int b = bh >> 4, h = bh & 15;
  const size_t qkbase = (size_t)b * T_DIM * C_DIM + (size_t)h * HD;
  const size_t vtbase = (size_t)b * T_DIM * C_DIM + (size_t)h * HD * T_DIM;
  const int tid = threadIdx.x, wid = tid >> 6, lane = tid & 63;
  const float scale2 = 0.08838834764831845f * 1.4426950408889634f;  // scale*log2(e)

  const int kr = tid >> 4, kc = (tid & 15) * 8;
  const int vr = tid >> 3, vc = (tid & 7) * 8;
  const u16* Kgp = Kg + qkbase + (size_t)kr * C_DIM + kc;
  const u16* Vgp = VtG + vtbase + (size_t)vr * T_DIM + vc;

  auto process = [&](int qb) {
    short8 qf[4];
    {
      const u16* qp = Qg + qkbase + (size_t)(qb + wid * 16 + (lane & 15)) * C_DIM + (lane >> 4) * 8;
#pragma unroll
      for (int dc = 0; dc < 4; ++dc) qf[dc] = *(const short8*)(qp + dc * 32);
    }
    f32x4 zero4 = {0.f, 0.f, 0.f, 0.f};
    f32x4 ao[8];
#pragma unroll
    for (int i = 0; i < 8; ++i) ao[i] = zero4;
    float m_run[4] = {-1e30f, -1e30f, -1e30f, -1e30f};
    float l_run[4] = {0.f, 0.f, 0.f, 0.f};
    const int myrow_lo = qb + wid * 16;
    const int qr0 = myrow_lo + (lane >> 4) * 4;
    const int nt = (qb >> 6) + 2;

    // prologue: load tile 0 into regs
    ushort8 kA = *(const ushort8*)(Kgp);
    ushort8 kB = *(const ushort8*)(Kgp + 32 * (size_t)C_DIM);
    ushort8 vA = *(const ushort8*)(Vgp);
    ushort8 vB = *(const ushort8*)(Vgp + 64 * (size_t)T_DIM);

    for (int t = 0; t < nt; ++t) {
      const int kb = t * 64;
      __syncthreads();   // LDS free (previous compute done)
      *(ushort8*)&Klds[kr][kc]      = kA;
      *(ushort8*)&Klds[kr + 32][kc] = kB;
      *(ushort8*)&Vlds[vr][vc]      = vA;
      *(ushort8*)&Vlds[vr + 64][vc] = vB;
      __syncthreads();   // LDS ready
      if (t + 1 < nt) {  // issue next-tile loads; latency hides under compute
        const int nkb = kb + 64;
        kA = *(const ushort8*)(Kgp + (size_t)nkb * C_DIM);
        kB = *(const ushort8*)(Kgp + (size_t)(nkb + 32) * C_DIM);
        vA = *(const ushort8*)(Vgp + nkb);
        vB = *(const ushort8*)(Vgp + 64 * (size_t)T_DIM + nkb);
      }

      if (kb <= myrow_lo + 15) {
        // S = Q K^T (16 x 64)
        f32x4 s[4];
        __builtin_amdgcn_s_setprio(1);
#pragma unroll
        for (int jt = 0; jt < 4; ++jt) {
          f32x4 a = zero4;
#pragma unroll
          for (int dc = 0; dc < 4; ++dc) {
            short8 kf = *(const short8*)&Klds[jt * 16 + (lane & 15)][dc * 32 + (lane >> 4) * 8];
            a = __builtin_amdgcn_mfma_f32_16x16x32_bf16(qf[dc], kf, a, 0, 0, 0);
          }
          s[jt] = a;
        }
        __builtin_amdgcn_s_setprio(0);

        // scale (log2 domain) + causal mask
        const bool domask = (kb + 63) > myrow_lo;
#pragma unroll
        for (int jt = 0; jt < 4; ++jt) {
          const int kcol = kb + jt * 16 + (lane & 15);
#pragma unroll
          for (int r = 0; r < 4; ++r) {
            float sv = s[jt][r] * scale2;
            if (domask && (kcol > qr0 + r)) sv = -1e30f;
            s[jt][r] = sv;
          }
        }

        // row max over 16 lanes
        float mx[4];
#pragma unroll
        for (int r = 0; r < 4; ++r)
          mx[r] = fmaxf(fmaxf(s[0][r], s[1][r]), fmaxf(s[2][r], s[3][r]));
#pragma unroll
        for (int off = 1; off < 16; off <<= 1)
#pragma unroll
          for (int r = 0; r < 4; ++r) mx[r] = fmaxf(mx[r], __shfl_xor(mx[r], off, 64));

        // defer-max: rescale only when some row grew past m_run + 8
        int need = 0;
#pragma unroll
        for (int r = 0; r < 4; ++r) need |= (mx[r] > m_run[r] + 8.0f) ? 1 : 0;
        if (__any(need)) {
          float corr[4];
#pragma unroll
          for (int r = 0; r < 4; ++r) {
            float mn = fmaxf(m_run[r], mx[r]);
            corr[r] = __builtin_amdgcn_exp2f(m_run[r] - mn);
            m_run[r] = mn;
          }
#pragma unroll
          for (int dc = 0; dc < 8; ++dc)
#pragma unroll
            for (int r = 0; r < 4; ++r) ao[dc][r] *= corr[r];
#pragma unroll
          for (int r = 0; r < 4; ++r) l_run[r] *= corr[r];
        }

        float sm[4] = {0.f, 0.f, 0.f, 0.f};
#pragma unroll
        for (int jt = 0; jt < 4; ++jt)
#pragma unroll
          for (int r = 0; r < 4; ++r) {
            float p = __builtin_amdgcn_exp2f(s[jt][r] - m_run[r]);
            s[jt][r] = p;
            sm[r] += p;
          }
#pragma unroll
        for (int off = 1; off < 16; off <<= 1)
#pragma unroll
          for (int r = 0; r < 4; ++r) sm[r] += __shfl_xor(sm[r], off, 64);
#pragma unroll
        for (int r = 0; r < 4; ++r) l_run[r] += sm[r];

        // P -> per-wave LDS (A-fragment layout for PV)
#pragma unroll
        for (int jt = 0; jt < 4; ++jt)
#pragma unroll
          for (int r = 0; r < 4; ++r)
            Plds[wid][(lane >> 4) * 4 + r][jt * 16 + (lane & 15)] = f2bf(s[jt][r]);

        // O += P @ V
        __builtin_amdgcn_s_setprio(1);
#pragma unroll
        for (int dc = 0; dc < 8; ++dc) {
#pragma unroll
          for (int kc2 = 0; kc2 < 2; ++kc2) {
            short8 pf = *(const short8*)&Plds[wid][lane & 15][kc2 * 32 + (lane >> 4) * 8];
            short8 vf = *(const short8*)&Vlds[dc * 16 + (lane & 15)][kc2 * 32 + (lane >> 4) * 8];
            ao[dc] = __builtin_amdgcn_mfma_f32_16x16x32_bf16(pf, vf, ao[dc], 0, 0, 0);
          }
        }
        __builtin_amdgcn_s_setprio(0);
      }
    }

    float rcp[4];
#pragma unroll
    for (int r = 0; r < 4; ++r) rcp[r] = 1.0f / l_run[r];
    u16* yp = Y + qkbase + (size_t)(qb + wid * 16 + (lane >> 4) * 4) * C_DIM + (lane & 15);
#pragma unroll
    for (int dc = 0; dc < 8; ++dc)
#pragma unroll
      for (int r = 0; r < 4; ++r)
        yp[(size_t)r * C_DIM + dc * 16] = f2bf(ao[dc][r] * rcp[r]);
  };

  process(pair * 128);
  process((15 - pair) * 128);
}

extern "C" void kernel_launch(void* const* d_in, const int* in_sizes, int n_in,
                              void* d_out, int out_size, void* d_ws, size_t ws_size,
                              hipStream_t stream) {
  const float* x  = (const float*)d_in[0];
  const float* Wq = (const float*)d_in[1];
  const float* Wk = (const float*)d_in[2];
  const float* Wv = (const float*)d_in[3];
  const float* Wo = (const float*)d_in[4];
  float* out = (float*)d_out;

  const size_t SZX = (size_t)8192 * 2048;
  const size_t SZW = (size_t)2048 * 2048;
  u16* xb  = (u16*)d_ws;
  u16* Wqb = xb + SZX;
  u16* Wkb = Wqb + SZW;
  u16* Wvb = Wkb + SZW;
  u16* Wob = Wvb + SZW;
  u16* Qb  = Wob + SZW;   // Q, overwritten in place by attention output Y
  u16* Kb  = Qb + SZX;
  u16* Vb  = Kb + SZX;    // V^T in [b][n][t] layout

  cast_bf16_kernel<<<(int)(SZX / 2048), 256, 0, stream>>>(x,  xb,  (int)SZX);
  cast_bf16_kernel<<<(int)(SZW / 2048), 256, 0, stream>>>(Wq, Wqb, (int)SZW);
  cast_bf16_kernel<<<(int)(SZW / 2048), 256, 0, stream>>>(Wk, Wkb, (int)SZW);
  cast_bf16_kernel<<<(int)(SZW / 2048), 256, 0, stream>>>(Wv, Wvb, (int)SZW);
  cast_bf16_kernel<<<(int)(SZW / 2048), 256, 0, stream>>>(Wo, Wob, (int)SZW);

  gemm_bt<0><<<1024, 256, 0, stream>>>(xb, Wqb, Qb, 8192, 2048, 2048);
  gemm_bt<0><<<1024, 256, 0, stream>>>(xb, Wkb, Kb, 8192, 2048, 2048);
  gemm_bt<2><<<1024, 256, 0, stream>>>(xb, Wvb, Vb, 8192, 2048, 2048);  // V^T out

  attn_kernel<<<dim3(8, B_DIM * NH), 512, 0, stream>>>(Qb, Kb, Vb, Qb);

  gemm_bt<1><<<1024, 256, 0, stream>>>(Qb, Wob, out, 8192, 2048, 2048);
}

// Round 5
// 469.271 us; speedup vs baseline: 2.4156x; 1.2190x over previous
//
#include <hip/hip_runtime.h>
#include <stdint.h>

#define B_DIM 4
#define T_DIM 2048
#define C_DIM 2048
#define NH 16
#define HD 128

typedef unsigned short u16;
typedef __attribute__((ext_vector_type(8))) short short8;
typedef __attribute__((ext_vector_type(8))) u16 ushort8;
typedef __attribute__((ext_vector_type(4))) u16 u16x4;
typedef __attribute__((ext_vector_type(4))) float f32x4;

__device__ __forceinline__ u16 f2bf(float f) {
  uint32_t u = __builtin_bit_cast(uint32_t, f);
  u = (u + 0x7FFFu + ((u >> 16) & 1u)) >> 16;
  return (u16)u;
}

__device__ __forceinline__ void gload16(const void* g, void* l) {
  __builtin_amdgcn_global_load_lds(
      (const __attribute__((address_space(1))) void*)g,
      (__attribute__((address_space(3))) void*)l, 16, 0, 0);
}

__device__ __forceinline__ void wait_vm4() { asm volatile("s_waitcnt vmcnt(4)" ::: "memory"); }
__device__ __forceinline__ void wait_vm0() { asm volatile("s_waitcnt vmcnt(0)" ::: "memory"); }
__device__ __forceinline__ void wait_lg0() {
  asm volatile("s_waitcnt lgkmcnt(0)" ::: "memory");
  __builtin_amdgcn_sched_barrier(0);
}

// ---------------- cast f32 -> bf16, 8 elems/thread ----------------
__global__ void cast_bf16_kernel(const float* __restrict__ src, u16* __restrict__ dst, int n) {
  int i = (blockIdx.x * 256 + threadIdx.x) * 8;
  if (i >= n) return;
  f32x4 a = *(const f32x4*)(src + i);
  f32x4 b = *(const f32x4*)(src + i + 4);
  ushort8 o;
  o[0] = f2bf(a[0]); o[1] = f2bf(a[1]); o[2] = f2bf(a[2]); o[3] = f2bf(a[3]);
  o[4] = f2bf(b[0]); o[5] = f2bf(b[1]); o[6] = f2bf(b[2]); o[7] = f2bf(b[3]);
  *(ushort8*)(dst + i) = o;
}

// ---------------- NT GEMM, 256x256 tile, BK=64, 8 waves, 4-phase/K-tile ----
// C[m,n] = sum_k A[m,k]*B[n,k].  LDS = 8 ring slots of 16KiB; slot holds one
// operand's [256 rows][32 k] K-half, row-major (bank-uniform for both
// ds_read_b128 fragments and linear global_load_lds). Counted vmcnt(4) only —
// never drains to 0 in the loop (T3+T4). Stage targets are parity-opposite
// slots whose last reader finished >=2 barriers earlier (race-free).
// MODE 0: bf16 row-major out. MODE 1: f32 row-major out.
// MODE 2: bf16 out transposed per batch: C_t[b][n][t].
template<int MODE>
__global__ __launch_bounds__(512, 2)
void gemm256(const u16* __restrict__ A, const u16* __restrict__ Bw,
             void* __restrict__ Cout, int M, int N, int K) {
  __shared__ __align__(16) u16 lds[8][8192];
  const int nbn = N >> 8;
  const int cpx = gridDim.x >> 3;                     // grid % 8 == 0
  const int swz = (blockIdx.x & 7) * cpx + (blockIdx.x >> 3);
  const int bm = (swz / nbn) << 8;
  const int bn = (swz % nbn) << 8;
  const int tid = threadIdx.x, wid = tid >> 6, lane = tid & 63;
  const int wm = wid >> 2, wn = wid & 3;              // 2 x 4 waves

  // staging: per instr, wave covers 16 rows x 64B; i=1 adds 128 rows
  const int srow = (wid << 4) + (lane >> 2);
  const int scol = (lane & 3) << 3;
  const u16* Ag = A + (size_t)(bm + srow) * K + scol;
  const u16* Bg = Bw + (size_t)(bn + srow) * K + scol;
  const size_t rowStep = (size_t)128 * K;
  const int su = wid << 9;                            // u16 idx of wave's stage base

  // fragment read bases (u16 idx within a slot): [row][32k] rows
  const int arow = ((wm << 7) + (lane & 15)) * 32 + ((lane >> 4) << 3);
  const int brow = ((wn << 6) + (lane & 15)) * 32 + ((lane >> 4) << 3);

  f32x4 acc[8][4];
  f32x4 zero4 = {0.f, 0.f, 0.f, 0.f};
#pragma unroll
  for (int i = 0; i < 8; ++i)
#pragma unroll
    for (int n = 0; n < 4; ++n) acc[i][n] = zero4;

  auto stage2 = [&](const u16* s, int slot) {
    gload16(s, &lds[slot][su]);
    gload16(s + rowStep, &lds[slot][su + 4096]);
  };

  // prologue: tile 0 -> slots 0..3, order Akk0, Bkk0, Akk1, Bkk1
  stage2(Ag, 0); stage2(Bg, 2); stage2(Ag + 32, 1); stage2(Bg + 32, 3);

  short8 af[4], ah[4], bf[4];
  const int NT = K >> 6;                              // 32
#pragma unroll 2
  for (int t = 0; t < NT; ++t) {
    const int par = (t & 1) << 2;
    const int npar = par ^ 4;
    const int tc = ((t + 1) & (NT - 1)) << 6;         // last tile re-stages t0 (unused, safe)

    // ---- P1: kk0, m0-3 ----
    wait_vm4();                                        // oldest 4 = {Akk0,Bkk0}(t)
    __builtin_amdgcn_s_barrier();
#pragma unroll
    for (int i = 0; i < 4; ++i) af[i] = *(const short8*)&lds[par][arow + i * 512];
#pragma unroll
    for (int n = 0; n < 4; ++n) bf[n] = *(const short8*)&lds[par + 2][brow + n * 512];
    stage2(Ag + tc, npar);
    __builtin_amdgcn_s_barrier();
    wait_lg0();
    __builtin_amdgcn_s_setprio(1);
#pragma unroll
    for (int i = 0; i < 4; ++i)
#pragma unroll
      for (int n = 0; n < 4; ++n)
        acc[i][n] = __builtin_amdgcn_mfma_f32_16x16x32_bf16(af[i], bf[n], acc[i][n], 0, 0, 0);
    __builtin_amdgcn_s_setprio(0);

    // ---- P2: kk0, m4-7 ----
#pragma unroll
    for (int i = 0; i < 4; ++i) ah[i] = *(const short8*)&lds[par][arow + 2048 + i * 512];
    stage2(Bg + tc, npar + 2);
    __builtin_amdgcn_s_barrier();
    wait_lg0();
    __builtin_amdgcn_s_setprio(1);
#pragma unroll
    for (int i = 0; i < 4; ++i)
#pragma unroll
      for (int n = 0; n < 4; ++n)
        acc[4 + i][n] = __builtin_amdgcn_mfma_f32_16x16x32_bf16(ah[i], bf[n], acc[4 + i][n], 0, 0, 0);
    __builtin_amdgcn_s_setprio(0);

    // ---- P3: kk1, m0-3 ----
    wait_vm4();                                        // oldest 4 = {Akk1,Bkk1}(t)
    __builtin_amdgcn_s_barrier();
#pragma unroll
    for (int i = 0; i < 4; ++i) af[i] = *(const short8*)&lds[par + 1][arow + i * 512];
#pragma unroll
    for (int n = 0; n < 4; ++n) bf[n] = *(const short8*)&lds[par + 3][brow + n * 512];
    stage2(Ag + tc + 32, npar + 1);
    __builtin_amdgcn_s_barrier();
    wait_lg0();
    __builtin_amdgcn_s_setprio(1);
#pragma unroll
    for (int i = 0; i < 4; ++i)
#pragma unroll
      for (int n = 0; n < 4; ++n)
        acc[i][n] = __builtin_amdgcn_mfma_f32_16x16x32_bf16(af[i], bf[n], acc[i][n], 0, 0, 0);
    __builtin_amdgcn_s_setprio(0);

    // ---- P4: kk1, m4-7 ----
#pragma unroll
    for (int i = 0; i < 4; ++i) ah[i] = *(const short8*)&lds[par + 1][arow + 2048 + i * 512];
    stage2(Bg + tc + 32, npar + 3);
    __builtin_amdgcn_s_barrier();
    wait_lg0();
    __builtin_amdgcn_s_setprio(1);
#pragma unroll
    for (int i = 0; i < 4; ++i)
#pragma unroll
      for (int n = 0; n < 4; ++n)
        acc[4 + i][n] = __builtin_amdgcn_mfma_f32_16x16x32_bf16(ah[i], bf[n], acc[4 + i][n], 0, 0, 0);
    __builtin_amdgcn_s_setprio(0);
  }
  wait_vm0();   // drain dangling wrap-around stages before reuse/exit

  // ---- epilogue: D row=(l>>4)*4+r, col=l&15 ----
  const int orow = (lane >> 4) << 2;
  const int ocol = lane & 15;
#pragma unroll
  for (int mi = 0; mi < 8; ++mi)
#pragma unroll
    for (int ni = 0; ni < 4; ++ni) {
      f32x4 v = acc[mi][ni];
      const int row0 = (wm << 7) + mi * 16 + orow;
      const int col = bn + (wn << 6) + ni * 16 + ocol;
      if (MODE == 2) {
        u16* C = (u16*)Cout;
        size_t base = (size_t)(bm >> 11) * ((size_t)T_DIM * C_DIM) +
                      (size_t)col * T_DIM + (size_t)((bm & 2047) + row0);
        u16x4 o;
        o[0] = f2bf(v[0]); o[1] = f2bf(v[1]); o[2] = f2bf(v[2]); o[3] = f2bf(v[3]);
        *(u16x4*)&C[base] = o;
      } else {
        size_t base = (size_t)(bm + row0) * N + col;
        if (MODE == 1) {
          float* C = (float*)Cout;
#pragma unroll
          for (int r = 0; r < 4; ++r) C[base + (size_t)r * N] = v[r];
        } else {
          u16* C = (u16*)Cout;
#pragma unroll
          for (int r = 0; r < 4; ++r) C[base + (size_t)r * N] = f2bf(v[r]);
        }
      }
    }
}

// ---------------- causal flash attention ----------------
// grid (8, B*H), 512 threads. Block p processes q-blocks p and 15-p (128 rows
// each) sequentially -> 34 KV tiles per block, perfectly balanced.
// Async-STAGE: next tile's K/V global->regs issued under current compute.
__global__ __launch_bounds__(512)
void attn_kernel(const u16* __restrict__ Qg, const u16* __restrict__ Kg,
                 const u16* __restrict__ VtG, u16* __restrict__ Y) {
  __shared__ __align__(16) u16 Klds[64][136];
  __shared__ __align__(16) u16 Vlds[128][72];
  __shared__ __align__(16) u16 Plds[8][16][72];
  const int pair = blockIdx.x;
  const int bh = blockIdx.y;
  const int b = bh >> 4, h = bh & 15;
  const size_t qkbase = (size_t)b * T_DIM * C_DIM + (size_t)h * HD;
  const size_t vtbase = (size_t)b * T_DIM * C_DIM + (size_t)h * HD * T_DIM;
  const int tid = threadIdx.x, wid = tid >> 6, lane = tid & 63;
  const float scale2 = 0.08838834764831845f * 1.4426950408889634f;  // scale*log2(e)

  const int kr = tid >> 4, kc = (tid & 15) * 8;
  const int vr = tid >> 3, vc = (tid & 7) * 8;
  const u16* Kgp = Kg + qkbase + (size_t)kr * C_DIM + kc;
  const u16* Vgp = VtG + vtbase + (size_t)vr * T_DIM + vc;

  auto process = [&](int qb) {
    short8 qf[4];
    {
      const u16* qp = Qg + qkbase + (size_t)(qb + wid * 16 + (lane & 15)) * C_DIM + (lane >> 4) * 8;
#pragma unroll
      for (int dc = 0; dc < 4; ++dc) qf[dc] = *(const short8*)(qp + dc * 32);
    }
    f32x4 zero4 = {0.f, 0.f, 0.f, 0.f};
    f32x4 ao[8];
#pragma unroll
    for (int i = 0; i < 8; ++i) ao[i] = zero4;
    float m_run[4] = {-1e30f, -1e30f, -1e30f, -1e30f};
    float l_run[4] = {0.f, 0.f, 0.f, 0.f};
    const int myrow_lo = qb + wid * 16;
    const int qr0 = myrow_lo + (lane >> 4) * 4;
    const int nt = (qb >> 6) + 2;

    // prologue: load tile 0 into regs
    ushort8 kA = *(const ushort8*)(Kgp);
    ushort8 kB = *(const ushort8*)(Kgp + 32 * (size_t)C_DIM);
    ushort8 vA = *(const ushort8*)(Vgp);
    ushort8 vB = *(const ushort8*)(Vgp + 64 * (size_t)T_DIM);

    for (int t = 0; t < nt; ++t) {
      const int kb = t * 64;
      __syncthreads();   // LDS free (previous compute done)
      *(ushort8*)&Klds[kr][kc]      = kA;
      *(ushort8*)&Klds[kr + 32][kc] = kB;
      *(ushort8*)&Vlds[vr][vc]      = vA;
      *(ushort8*)&Vlds[vr + 64][vc] = vB;
      __syncthreads();   // LDS ready
      if (t + 1 < nt) {  // issue next-tile loads; latency hides under compute
        const int nkb = kb + 64;
        kA = *(const ushort8*)(Kgp + (size_t)nkb * C_DIM);
        kB = *(const ushort8*)(Kgp + (size_t)(nkb + 32) * C_DIM);
        vA = *(const ushort8*)(Vgp + nkb);
        vB = *(const ushort8*)(Vgp + 64 * (size_t)T_DIM + nkb);
      }

      if (kb <= myrow_lo + 15) {
        // S = Q K^T (16 x 64)
        f32x4 s[4];
        __builtin_amdgcn_s_setprio(1);
#pragma unroll
        for (int jt = 0; jt < 4; ++jt) {
          f32x4 a = zero4;
#pragma unroll
          for (int dc = 0; dc < 4; ++dc) {
            short8 kf = *(const short8*)&Klds[jt * 16 + (lane & 15)][dc * 32 + (lane >> 4) * 8];
            a = __builtin_amdgcn_mfma_f32_16x16x32_bf16(qf[dc], kf, a, 0, 0, 0);
          }
          s[jt] = a;
        }
        __builtin_amdgcn_s_setprio(0);

        // scale (log2 domain) + causal mask
        const bool domask = (kb + 63) > myrow_lo;
#pragma unroll
        for (int jt = 0; jt < 4; ++jt) {
          const int kcol = kb + jt * 16 + (lane & 15);
#pragma unroll
          for (int r = 0; r < 4; ++r) {
            float sv = s[jt][r] * scale2;
            if (domask && (kcol > qr0 + r)) sv = -1e30f;
            s[jt][r] = sv;
          }
        }

        // row max over 16 lanes
        float mx[4];
#pragma unroll
        for (int r = 0; r < 4; ++r)
          mx[r] = fmaxf(fmaxf(s[0][r], s[1][r]), fmaxf(s[2][r], s[3][r]));
#pragma unroll
        for (int off = 1; off < 16; off <<= 1)
#pragma unroll
          for (int r = 0; r < 4; ++r) mx[r] = fmaxf(mx[r], __shfl_xor(mx[r], off, 64));

        // defer-max: rescale only when some row grew past m_run + 8
        int need = 0;
#pragma unroll
        for (int r = 0; r < 4; ++r) need |= (mx[r] > m_run[r] + 8.0f) ? 1 : 0;
        if (__any(need)) {
          float corr[4];
#pragma unroll
          for (int r = 0; r < 4; ++r) {
            float mn = fmaxf(m_run[r], mx[r]);
            corr[r] = __builtin_amdgcn_exp2f(m_run[r] - mn);
            m_run[r] = mn;
          }
#pragma unroll
          for (int dc = 0; dc < 8; ++dc)
#pragma unroll
            for (int r = 0; r < 4; ++r) ao[dc][r] *= corr[r];
#pragma unroll
          for (int r = 0; r < 4; ++r) l_run[r] *= corr[r];
        }

        float sm[4] = {0.f, 0.f, 0.f, 0.f};
#pragma unroll
        for (int jt = 0; jt < 4; ++jt)
#pragma unroll
          for (int r = 0; r < 4; ++r) {
            float p = __builtin_amdgcn_exp2f(s[jt][r] - m_run[r]);
            s[jt][r] = p;
            sm[r] += p;
          }
#pragma unroll
        for (int off = 1; off < 16; off <<= 1)
#pragma unroll
          for (int r = 0; r < 4; ++r) sm[r] += __shfl_xor(sm[r], off, 64);
#pragma unroll
        for (int r = 0; r < 4; ++r) l_run[r] += sm[r];

        // P -> per-wave LDS (A-fragment layout for PV)
#pragma unroll
        for (int jt = 0; jt < 4; ++jt)
#pragma unroll
          for (int r = 0; r < 4; ++r)
            Plds[wid][(lane >> 4) * 4 + r][jt * 16 + (lane & 15)] = f2bf(s[jt][r]);

        // O += P @ V
        __builtin_amdgcn_s_setprio(1);
#pragma unroll
        for (int dc = 0; dc < 8; ++dc) {
#pragma unroll
          for (int kc2 = 0; kc2 < 2; ++kc2) {
            short8 pf = *(const short8*)&Plds[wid][lane & 15][kc2 * 32 + (lane >> 4) * 8];
            short8 vf = *(const short8*)&Vlds[dc * 16 + (lane & 15)][kc2 * 32 + (lane >> 4) * 8];
            ao[dc] = __builtin_amdgcn_mfma_f32_16x16x32_bf16(pf, vf, ao[dc], 0, 0, 0);
          }
        }
        __builtin_amdgcn_s_setprio(0);
      }
    }

    float rcp[4];
#pragma unroll
    for (int r = 0; r < 4; ++r) rcp[r] = 1.0f / l_run[r];
    u16* yp = Y + qkbase + (size_t)(qb + wid * 16 + (lane >> 4) * 4) * C_DIM + (lane & 15);
#pragma unroll
    for (int dc = 0; dc < 8; ++dc)
#pragma unroll
      for (int r = 0; r < 4; ++r)
        yp[(size_t)r * C_DIM + dc * 16] = f2bf(ao[dc][r] * rcp[r]);
  };

  process(pair * 128);
  process((15 - pair) * 128);
}

extern "C" void kernel_launch(void* const* d_in, const int* in_sizes, int n_in,
                              void* d_out, int out_size, void* d_ws, size_t ws_size,
                              hipStream_t stream) {
  const float* x  = (const float*)d_in[0];
  const float* Wq = (const float*)d_in[1];
  const float* Wk = (const float*)d_in[2];
  const float* Wv = (const float*)d_in[3];
  const float* Wo = (const float*)d_in[4];
  float* out = (float*)d_out;

  const size_t SZX = (size_t)8192 * 2048;
  const size_t SZW = (size_t)2048 * 2048;
  u16* xb  = (u16*)d_ws;
  u16* Wqb = xb + SZX;
  u16* Wkb = Wqb + SZW;
  u16* Wvb = Wkb + SZW;
  u16* Wob = Wvb + SZW;
  u16* Qb  = Wob + SZW;   // Q, overwritten in place by attention output Y
  u16* Kb  = Qb + SZX;
  u16* Vb  = Kb + SZX;    // V^T in [b][n][t] layout

  cast_bf16_kernel<<<(int)(SZX / 2048), 256, 0, stream>>>(x,  xb,  (int)SZX);
  cast_bf16_kernel<<<(int)(SZW / 2048), 256, 0, stream>>>(Wq, Wqb, (int)SZW);
  cast_bf16_kernel<<<(int)(SZW / 2048), 256, 0, stream>>>(Wk, Wkb, (int)SZW);
  cast_bf16_kernel<<<(int)(SZW / 2048), 256, 0, stream>>>(Wv, Wvb, (int)SZW);
  cast_bf16_kernel<<<(int)(SZW / 2048), 256, 0, stream>>>(Wo, Wob, (int)SZW);

  gemm256<0><<<256, 512, 0, stream>>>(xb, Wqb, Qb, 8192, 2048, 2048);
  gemm256<0><<<256, 512, 0, stream>>>(xb, Wkb, Kb, 8192, 2048, 2048);
  gemm256<2><<<256, 512, 0, stream>>>(xb, Wvb, Vb, 8192, 2048, 2048);  // V^T out

  attn_kernel<<<dim3(8, B_DIM * NH), 512, 0, stream>>>(Qb, Kb, Vb, Qb);

  gemm256<1><<<256, 512, 0, stream>>>(Qb, Wob, out, 8192, 2048, 2048);
}

// Round 6
// 455.965 us; speedup vs baseline: 2.4861x; 1.0292x over previous
//
#include <hip/hip_runtime.h>
#include <stdint.h>

#define B_DIM 4
#define T_DIM 2048
#define C_DIM 2048
#define NH 16
#define HD 128

typedef unsigned short u16;
typedef __attribute__((ext_vector_type(8))) short short8;
typedef __attribute__((ext_vector_type(8))) u16 ushort8;
typedef __attribute__((ext_vector_type(4))) u16 u16x4;
typedef __attribute__((ext_vector_type(4))) float f32x4;

__device__ __forceinline__ u16 f2bf(float f) {
  uint32_t u = __builtin_bit_cast(uint32_t, f);
  u = (u + 0x7FFFu + ((u >> 16) & 1u)) >> 16;
  return (u16)u;
}

__device__ __forceinline__ void gload16(const void* g, void* l) {
  __builtin_amdgcn_global_load_lds(
      (const __attribute__((address_space(1))) void*)g,
      (__attribute__((address_space(3))) void*)l, 16, 0, 0);
}

__device__ __forceinline__ void wait_vm2() { asm volatile("s_waitcnt vmcnt(2)" ::: "memory"); }
__device__ __forceinline__ void wait_vm0() { asm volatile("s_waitcnt vmcnt(0)" ::: "memory"); }
__device__ __forceinline__ void wait_lg0() {
  asm volatile("s_waitcnt lgkmcnt(0)" ::: "memory");
  __builtin_amdgcn_sched_barrier(0);
}

// ---------------- cast f32 -> bf16, 8 elems/thread ----------------
__global__ void cast_bf16_kernel(const float* __restrict__ src, u16* __restrict__ dst, int n) {
  int i = (blockIdx.x * 256 + threadIdx.x) * 8;
  if (i >= n) return;
  f32x4 a = *(const f32x4*)(src + i);
  f32x4 b = *(const f32x4*)(src + i + 4);
  ushort8 o;
  o[0] = f2bf(a[0]); o[1] = f2bf(a[1]); o[2] = f2bf(a[2]); o[3] = f2bf(a[3]);
  o[4] = f2bf(b[0]); o[5] = f2bf(b[1]); o[6] = f2bf(b[2]); o[7] = f2bf(b[3]);
  *(ushort8*)(dst + i) = o;
}

// ---------------- NT GEMM, 256x256 tile, BK=64, 8 waves, 4-phase/K-tile ----
// C[m,n] = sum_k A[m,k]*B[n,k]. LDS = 4 ring slots of 32KiB: full operand
// tiles [256 rows][64 k], 128B rows, XOR-swizzled (16B-unit ^= row&7) so
// fragment ds_read_b128 is conflict-free (T2, both-sides swizzle: pre-swizzled
// global source column + swizzled read). Counted vmcnt(2) at P1/P2 only (T4).
// Stage schedule per tile: P1:B{0,64} P2:B{128,192} P3:A{0,128} P4:A{64,192}.
// MODE 0: bf16 row-major out. MODE 1: f32 out. MODE 2: bf16 V^T out.
template<int MODE>
__global__ __launch_bounds__(512, 2)
void gemm256(const u16* __restrict__ A, const u16* __restrict__ Bw,
             void* __restrict__ Cout, int M, int N, int K) {
  __shared__ __align__(16) u16 lds[4][16384];
  const int nbn = N >> 8;
  const int cpx = gridDim.x >> 3;                     // grid % 8 == 0
  const int swz = (blockIdx.x & 7) * cpx + (blockIdx.x >> 3);
  const int bm = (swz / nbn) << 8;
  const int bn = (swz % nbn) << 8;
  const int tid = threadIdx.x, wid = tid >> 6, lane = tid & 63;
  const int wm = wid >> 2, wn = wid & 3;              // 2 x 4 waves

  // staging: one gload = 8 rows x 128B. lane: row += lane>>3, source column
  // pre-swizzled: unit = (lane&7) ^ (lane>>3)  (row&7 == lane>>3 always).
  const int srow = (wid << 3) + (lane >> 3);
  const int scol = ((lane & 7) ^ (lane >> 3)) << 3;
  const u16* Ag = A + (size_t)(bm + srow) * K + scol;
  const u16* Bg = Bw + (size_t)(bn + srow) * K + scol;
  const int sbase = wid << 9;                         // + row0*64 (u16 idx)

  // fragment reads: row = base + (l&15) (+16i, +64), unit = (kk*4+(l>>4)) ^ (l&7)
  const int l15 = lane & 15;
  const int o0 = ((lane >> 4) ^ (lane & 7)) << 3;
  const int o1 = ((4 | (lane >> 4)) ^ (lane & 7)) << 3;
  const int ar = ((wm << 7) + l15) << 6;
  const int br = ((wn << 6) + l15) << 6;

  f32x4 acc[8][4];
  f32x4 zero4 = {0.f, 0.f, 0.f, 0.f};
#pragma unroll
  for (int i = 0; i < 8; ++i)
#pragma unroll
    for (int n = 0; n < 4; ++n) acc[i][n] = zero4;

  auto stA = [&](int slot, int tc, int r0, int r1) {
    gload16(Ag + (size_t)r0 * K + tc, &lds[slot][(r0 << 6) + sbase]);
    gload16(Ag + (size_t)r1 * K + tc, &lds[slot][(r1 << 6) + sbase]);
  };
  auto stB = [&](int slot, int tc, int r0, int r1) {
    gload16(Bg + (size_t)r0 * K + tc, &lds[slot][(r0 << 6) + sbase]);
    gload16(Bg + (size_t)r1 * K + tc, &lds[slot][(r1 << 6) + sbase]);
  };

  // prologue: tile 0. Order matters for vmcnt accounting: B01,B23,A01,A23.
  stB(2, 0, 0, 64); stB(2, 0, 128, 192);
  stA(0, 0, 0, 128); stA(0, 0, 64, 192);

  short8 af[4], bf[4];
  const int NT = K >> 6;
#pragma unroll 2
  for (int t = 0; t < NT; ++t) {
    const int p = t & 1, q = p ^ 1;
    const int tc = ((t + 1) & (NT - 1)) << 6;         // wrap: last tile re-stages t0

    // ---- P1: kk0, acc rows 0-3 ----
    wait_vm2();                                        // drains B(t) all + A(t){0,128}
    __builtin_amdgcn_s_barrier();
#pragma unroll
    for (int i = 0; i < 4; ++i) af[i] = *(const short8*)&lds[p][ar + (i << 10) + o0];
#pragma unroll
    for (int n = 0; n < 4; ++n) bf[n] = *(const short8*)&lds[2 + p][br + (n << 10) + o0];
    stB(2 + q, tc, 0, 64);
    __builtin_amdgcn_s_barrier();
    wait_lg0();
    __builtin_amdgcn_s_setprio(1);
#pragma unroll
    for (int i = 0; i < 4; ++i)
#pragma unroll
      for (int n = 0; n < 4; ++n)
        acc[i][n] = __builtin_amdgcn_mfma_f32_16x16x32_bf16(af[i], bf[n], acc[i][n], 0, 0, 0);
    __builtin_amdgcn_s_setprio(0);

    // ---- P2: kk0, acc rows 4-7 ----
    wait_vm2();                                        // drains A(t){64,192}
    __builtin_amdgcn_s_barrier();
#pragma unroll
    for (int i = 0; i < 4; ++i) af[i] = *(const short8*)&lds[p][ar + 4096 + (i << 10) + o0];
    stB(2 + q, tc, 128, 192);
    __builtin_amdgcn_s_barrier();
    wait_lg0();
    __builtin_amdgcn_s_setprio(1);
#pragma unroll
    for (int i = 0; i < 4; ++i)
#pragma unroll
      for (int n = 0; n < 4; ++n)
        acc[4 + i][n] = __builtin_amdgcn_mfma_f32_16x16x32_bf16(af[i], bf[n], acc[4 + i][n], 0, 0, 0);
    __builtin_amdgcn_s_setprio(0);

    // ---- P3: kk1, acc rows 0-3 ----
    __builtin_amdgcn_s_barrier();
#pragma unroll
    for (int i = 0; i < 4; ++i) af[i] = *(const short8*)&lds[p][ar + (i << 10) + o1];
#pragma unroll
    for (int n = 0; n < 4; ++n) bf[n] = *(const short8*)&lds[2 + p][br + (n << 10) + o1];
    stA(q, tc, 0, 128);
    __builtin_amdgcn_s_barrier();
    wait_lg0();
    __builtin_amdgcn_s_setprio(1);
#pragma unroll
    for (int i = 0; i < 4; ++i)
#pragma unroll
      for (int n = 0; n < 4; ++n)
        acc[i][n] = __builtin_amdgcn_mfma_f32_16x16x32_bf16(af[i], bf[n], acc[i][n], 0, 0, 0);
    __builtin_amdgcn_s_setprio(0);

    // ---- P4: kk1, acc rows 4-7 ----
    __builtin_amdgcn_s_barrier();
#pragma unroll
    for (int i = 0; i < 4; ++i) af[i] = *(const short8*)&lds[p][ar + 4096 + (i << 10) + o1];
    stA(q, tc, 64, 192);
    __builtin_amdgcn_s_barrier();
    wait_lg0();
    __builtin_amdgcn_s_setprio(1);
#pragma unroll
    for (int i = 0; i < 4; ++i)
#pragma unroll
      for (int n = 0; n < 4; ++n)
        acc[4 + i][n] = __builtin_amdgcn_mfma_f32_16x16x32_bf16(af[i], bf[n], acc[4 + i][n], 0, 0, 0);
    __builtin_amdgcn_s_setprio(0);
  }
  wait_vm0();   // drain wrap-around stages

  // ---- epilogue: D row=(l>>4)*4+r, col=l&15 ----
  const int orow = (lane >> 4) << 2;
  const int ocol = lane & 15;
#pragma unroll
  for (int mi = 0; mi < 8; ++mi)
#pragma unroll
    for (int ni = 0; ni < 4; ++ni) {
      f32x4 v = acc[mi][ni];
      const int row0 = (wm << 7) + mi * 16 + orow;
      const int col = bn + (wn << 6) + ni * 16 + ocol;
      if (MODE == 2) {
        u16* C = (u16*)Cout;
        size_t base = (size_t)(bm >> 11) * ((size_t)T_DIM * C_DIM) +
                      (size_t)col * T_DIM + (size_t)((bm & 2047) + row0);
        u16x4 o;
        o[0] = f2bf(v[0]); o[1] = f2bf(v[1]); o[2] = f2bf(v[2]); o[3] = f2bf(v[3]);
        *(u16x4*)&C[base] = o;
      } else {
        size_t base = (size_t)(bm + row0) * N + col;
        if (MODE == 1) {
          float* C = (float*)Cout;
#pragma unroll
          for (int r = 0; r < 4; ++r) C[base + (size_t)r * N] = v[r];
        } else {
          u16* C = (u16*)Cout;
#pragma unroll
          for (int r = 0; r < 4; ++r) C[base + (size_t)r * N] = f2bf(v[r]);
        }
      }
    }
}

// ---------------- causal flash attention ----------------
// grid (512), 256 threads = 4 waves x 32 q-rows. Block id f: bh = (f&7)|((f>>6)<<3)
// (XCD-swizzle: all 8 pair-blocks of a head share one XCD's L2), pair=(f>>3)&7;
// processes q-blocks pair and 15-pair (128 rows each) -> 34 KV tiles, balanced.
// K/V fragment LDS reads amortized over 2 row-groups per wave.
__global__ __launch_bounds__(256, 2)
void attn_kernel(const u16* __restrict__ Qg, const u16* __restrict__ Kg,
                 const u16* __restrict__ VtG, u16* __restrict__ Y) {
  __shared__ __align__(16) u16 Klds[64][136];
  __shared__ __align__(16) u16 Vlds[128][72];
  __shared__ __align__(16) u16 Plds[4][32][72];
  const int f = blockIdx.x;
  const int pair = (f >> 3) & 7;
  const int bh = (f & 7) | ((f >> 6) << 3);
  const int b = bh >> 4, h = bh & 15;
  const size_t qkbase = (size_t)b * T_DIM * C_DIM + (size_t)h * HD;
  const size_t vtbase = (size_t)b * T_DIM * C_DIM + (size_t)h * HD * T_DIM;
  const int tid = threadIdx.x, wid = tid >> 6, lane = tid & 63;
  const float scale2 = 0.08838834764831845f * 1.4426950408889634f;  // scale*log2(e)

  const int kr = tid >> 4, kc = (tid & 15) * 8;   // K rows kr+16j
  const int vr = tid >> 3, vc = (tid & 7) * 8;    // V rows vr+32j
  const u16* Kgp = Kg + qkbase + (size_t)kr * C_DIM + kc;
  const u16* Vgp = VtG + vtbase + (size_t)vr * T_DIM + vc;

  auto process = [&](int qb) {
    const int rlo = qb + wid * 32;
    short8 qf[2][4];
#pragma unroll
    for (int rg = 0; rg < 2; ++rg) {
      const u16* qp = Qg + qkbase + (size_t)(rlo + rg * 16 + (lane & 15)) * C_DIM + (lane >> 4) * 8;
#pragma unroll
      for (int dc = 0; dc < 4; ++dc) qf[rg][dc] = *(const short8*)(qp + dc * 32);
    }
    f32x4 zero4 = {0.f, 0.f, 0.f, 0.f};
    f32x4 ao[2][8];
#pragma unroll
    for (int rg = 0; rg < 2; ++rg)
#pragma unroll
      for (int i = 0; i < 8; ++i) ao[rg][i] = zero4;
    float m_run[2][4], l_run[2][4];
#pragma unroll
    for (int rg = 0; rg < 2; ++rg)
#pragma unroll
      for (int r = 0; r < 4; ++r) { m_run[rg][r] = -1e30f; l_run[rg][r] = 0.f; }
    const int nt = (qb >> 6) + 2;

    ushort8 kN[4], vN[4];
#pragma unroll
    for (int j = 0; j < 4; ++j) {
      kN[j] = *(const ushort8*)(Kgp + (size_t)(16 * j) * C_DIM);
      vN[j] = *(const ushort8*)(Vgp + (size_t)(32 * j) * T_DIM);
    }

    for (int t = 0; t < nt; ++t) {
      const int kb = t * 64;
      __syncthreads();   // LDS free
#pragma unroll
      for (int j = 0; j < 4; ++j) {
        *(ushort8*)&Klds[kr + 16 * j][kc] = kN[j];
        *(ushort8*)&Vlds[vr + 32 * j][vc] = vN[j];
      }
      __syncthreads();   // LDS ready
      if (t + 1 < nt) {  // async-STAGE: next tile under current compute
        const int nkb = kb + 64;
#pragma unroll
        for (int j = 0; j < 4; ++j) {
          kN[j] = *(const ushort8*)(Kgp + (size_t)(nkb + 16 * j) * C_DIM);
          vN[j] = *(const ushort8*)(Vgp + (size_t)(32 * j) * T_DIM + nkb);
        }
      }

      if (kb <= rlo + 31) {
#pragma unroll
        for (int rg = 0; rg < 2; ++rg) {
          const int qr0 = rlo + rg * 16 + (lane >> 4) * 4;
          f32x4 s[4];
          __builtin_amdgcn_s_setprio(1);
#pragma unroll
          for (int jt = 0; jt < 4; ++jt) {
            f32x4 a = zero4;
#pragma unroll
            for (int dc = 0; dc < 4; ++dc) {
              short8 kf = *(const short8*)&Klds[jt * 16 + (lane & 15)][dc * 32 + (lane >> 4) * 8];
              a = __builtin_amdgcn_mfma_f32_16x16x32_bf16(qf[rg][dc], kf, a, 0, 0, 0);
            }
            s[jt] = a;
          }
          __builtin_amdgcn_s_setprio(0);

          const bool domask = (kb + 63) > (rlo + rg * 16);
#pragma unroll
          for (int jt = 0; jt < 4; ++jt) {
            const int kcol = kb + jt * 16 + (lane & 15);
#pragma unroll
            for (int r = 0; r < 4; ++r) {
              float sv = s[jt][r] * scale2;
              if (domask && (kcol > qr0 + r)) sv = -1e30f;
              s[jt][r] = sv;
            }
          }

          float mx[4];
#pragma unroll
          for (int r = 0; r < 4; ++r)
            mx[r] = fmaxf(fmaxf(s[0][r], s[1][r]), fmaxf(s[2][r], s[3][r]));
#pragma unroll
          for (int off = 1; off < 16; off <<= 1)
#pragma unroll
            for (int r = 0; r < 4; ++r) mx[r] = fmaxf(mx[r], __shfl_xor(mx[r], off, 64));

          int need = 0;
#pragma unroll
          for (int r = 0; r < 4; ++r) need |= (mx[r] > m_run[rg][r] + 8.0f) ? 1 : 0;
          if (__any(need)) {
            float corr[4];
#pragma unroll
            for (int r = 0; r < 4; ++r) {
              float mn = fmaxf(m_run[rg][r], mx[r]);
              corr[r] = __builtin_amdgcn_exp2f(m_run[rg][r] - mn);
              m_run[rg][r] = mn;
            }
#pragma unroll
            for (int dc = 0; dc < 8; ++dc)
#pragma unroll
              for (int r = 0; r < 4; ++r) ao[rg][dc][r] *= corr[r];
#pragma unroll
            for (int r = 0; r < 4; ++r) l_run[rg][r] *= corr[r];
          }

          float sm[4] = {0.f, 0.f, 0.f, 0.f};
#pragma unroll
          for (int jt = 0; jt < 4; ++jt)
#pragma unroll
            for (int r = 0; r < 4; ++r) {
              float p = __builtin_amdgcn_exp2f(s[jt][r] - m_run[rg][r]);
              s[jt][r] = p;
              sm[r] += p;
            }
#pragma unroll
          for (int off = 1; off < 16; off <<= 1)
#pragma unroll
            for (int r = 0; r < 4; ++r) sm[r] += __shfl_xor(sm[r], off, 64);
#pragma unroll
          for (int r = 0; r < 4; ++r) l_run[rg][r] += sm[r];

#pragma unroll
          for (int jt = 0; jt < 4; ++jt)
#pragma unroll
            for (int r = 0; r < 4; ++r)
              Plds[wid][rg * 16 + (lane >> 4) * 4 + r][jt * 16 + (lane & 15)] = f2bf(s[jt][r]);
        }

        // PV: vf shared by both row-groups
        short8 pf[2][2];
#pragma unroll
        for (int rg = 0; rg < 2; ++rg)
#pragma unroll
          for (int k2 = 0; k2 < 2; ++k2)
            pf[rg][k2] = *(const short8*)&Plds[wid][rg * 16 + (lane & 15)][k2 * 32 + (lane >> 4) * 8];
        __builtin_amdgcn_s_setprio(1);
#pragma unroll
        for (int dc = 0; dc < 8; ++dc) {
#pragma unroll
          for (int k2 = 0; k2 < 2; ++k2) {
            short8 vf = *(const short8*)&Vlds[dc * 16 + (lane & 15)][k2 * 32 + (lane >> 4) * 8];
            ao[0][dc] = __builtin_amdgcn_mfma_f32_16x16x32_bf16(pf[0][k2], vf, ao[0][dc], 0, 0, 0);
            ao[1][dc] = __builtin_amdgcn_mfma_f32_16x16x32_bf16(pf[1][k2], vf, ao[1][dc], 0, 0, 0);
          }
        }
        __builtin_amdgcn_s_setprio(0);
      }
    }

#pragma unroll
    for (int rg = 0; rg < 2; ++rg) {
      float rcp[4];
#pragma unroll
      for (int r = 0; r < 4; ++r) rcp[r] = 1.0f / l_run[rg][r];
      u16* yp = Y + qkbase + (size_t)(rlo + rg * 16 + (lane >> 4) * 4) * C_DIM + (lane & 15);
#pragma unroll
      for (int dc = 0; dc < 8; ++dc)
#pragma unroll
        for (int r = 0; r < 4; ++r)
          yp[(size_t)r * C_DIM + dc * 16] = f2bf(ao[rg][dc][r] * rcp[r]);
    }
  };

  process(pair * 128);
  process((15 - pair) * 128);
}

extern "C" void kernel_launch(void* const* d_in, const int* in_sizes, int n_in,
                              void* d_out, int out_size, void* d_ws, size_t ws_size,
                              hipStream_t stream) {
  const float* x  = (const float*)d_in[0];
  const float* Wq = (const float*)d_in[1];
  const float* Wk = (const float*)d_in[2];
  const float* Wv = (const float*)d_in[3];
  const float* Wo = (const float*)d_in[4];
  float* out = (float*)d_out;

  const size_t SZX = (size_t)8192 * 2048;
  const size_t SZW = (size_t)2048 * 2048;
  u16* xb  = (u16*)d_ws;
  u16* Wqb = xb + SZX;
  u16* Wkb = Wqb + SZW;
  u16* Wvb = Wkb + SZW;
  u16* Wob = Wvb + SZW;
  u16* Qb  = Wob + SZW;   // Q, overwritten in place by attention output Y
  u16* Kb  = Qb + SZX;
  u16* Vb  = Kb + SZX;    // V^T in [b][n][t] layout

  cast_bf16_kernel<<<(int)(SZX / 2048), 256, 0, stream>>>(x,  xb,  (int)SZX);
  cast_bf16_kernel<<<(int)(SZW / 2048), 256, 0, stream>>>(Wq, Wqb, (int)SZW);
  cast_bf16_kernel<<<(int)(SZW / 2048), 256, 0, stream>>>(Wk, Wkb, (int)SZW);
  cast_bf16_kernel<<<(int)(SZW / 2048), 256, 0, stream>>>(Wv, Wvb, (int)SZW);
  cast_bf16_kernel<<<(int)(SZW / 2048), 256, 0, stream>>>(Wo, Wob, (int)SZW);

  gemm256<0><<<256, 512, 0, stream>>>(xb, Wqb, Qb, 8192, 2048, 2048);
  gemm256<0><<<256, 512, 0, stream>>>(xb, Wkb, Kb, 8192, 2048, 2048);
  gemm256<2><<<256, 512, 0, stream>>>(xb, Wvb, Vb, 8192, 2048, 2048);  // V^T out

  attn_kernel<<<512, 256, 0, stream>>>(Qb, Kb, Vb, Qb);

  gemm256<1><<<256, 512, 0, stream>>>(Qb, Wob, out, 8192, 2048, 2048);
}

// Round 7
// 384.264 us; speedup vs baseline: 2.9500x; 1.1866x over previous
//
#include <hip/hip_runtime.h>
#include <stdint.h>

#define B_DIM 4
#define T_DIM 2048
#define C_DIM 2048
#define NH 16
#define HD 128

typedef unsigned short u16;
typedef __attribute__((ext_vector_type(8))) short short8;
typedef __attribute__((ext_vector_type(8))) u16 ushort8;
typedef __attribute__((ext_vector_type(4))) u16 u16x4;
typedef __attribute__((ext_vector_type(4))) float f32x4;

__device__ __forceinline__ u16 f2bf(float f) {
  uint32_t u = __builtin_bit_cast(uint32_t, f);
  u = (u + 0x7FFFu + ((u >> 16) & 1u)) >> 16;
  return (u16)u;
}

__device__ __forceinline__ void gload16(const void* g, void* l) {
  __builtin_amdgcn_global_load_lds(
      (const __attribute__((address_space(1))) void*)g,
      (__attribute__((address_space(3))) void*)l, 16, 0, 0);
}

__device__ __forceinline__ void wait_vm2() { asm volatile("s_waitcnt vmcnt(2)" ::: "memory"); }
__device__ __forceinline__ void wait_vm0() { asm volatile("s_waitcnt vmcnt(0)" ::: "memory"); }
__device__ __forceinline__ void wait_lg0() {
  asm volatile("s_waitcnt lgkmcnt(0)" ::: "memory");
  __builtin_amdgcn_sched_barrier(0);
}

// ---------------- cast f32 -> bf16, 8 elems/thread ----------------
__global__ void cast_bf16_kernel(const float* __restrict__ src, u16* __restrict__ dst, int n) {
  int i = (blockIdx.x * 256 + threadIdx.x) * 8;
  if (i >= n) return;
  f32x4 a = *(const f32x4*)(src + i);
  f32x4 b = *(const f32x4*)(src + i + 4);
  ushort8 o;
  o[0] = f2bf(a[0]); o[1] = f2bf(a[1]); o[2] = f2bf(a[2]); o[3] = f2bf(a[3]);
  o[4] = f2bf(b[0]); o[5] = f2bf(b[1]); o[6] = f2bf(b[2]); o[7] = f2bf(b[3]);
  *(ushort8*)(dst + i) = o;
}

// ---------------- NT GEMM, 256x256 tile, BK=64, 8 waves, 4-phase/K-tile ----
// (unchanged from round 6; see comments there)
template<int MODE>
__global__ __launch_bounds__(512, 2)
void gemm256(const u16* __restrict__ A, const u16* __restrict__ Bw,
             void* __restrict__ Cout, int M, int N, int K) {
  __shared__ __align__(16) u16 lds[4][16384];
  const int nbn = N >> 8;
  const int cpx = gridDim.x >> 3;
  const int swz = (blockIdx.x & 7) * cpx + (blockIdx.x >> 3);
  const int bm = (swz / nbn) << 8;
  const int bn = (swz % nbn) << 8;
  const int tid = threadIdx.x, wid = tid >> 6, lane = tid & 63;
  const int wm = wid >> 2, wn = wid & 3;

  const int srow = (wid << 3) + (lane >> 3);
  const int scol = ((lane & 7) ^ (lane >> 3)) << 3;
  const u16* Ag = A + (size_t)(bm + srow) * K + scol;
  const u16* Bg = Bw + (size_t)(bn + srow) * K + scol;
  const int sbase = wid << 9;

  const int l15 = lane & 15;
  const int o0 = ((lane >> 4) ^ (lane & 7)) << 3;
  const int o1 = ((4 | (lane >> 4)) ^ (lane & 7)) << 3;
  const int ar = ((wm << 7) + l15) << 6;
  const int br = ((wn << 6) + l15) << 6;

  f32x4 acc[8][4];
  f32x4 zero4 = {0.f, 0.f, 0.f, 0.f};
#pragma unroll
  for (int i = 0; i < 8; ++i)
#pragma unroll
    for (int n = 0; n < 4; ++n) acc[i][n] = zero4;

  auto stA = [&](int slot, int tc, int r0, int r1) {
    gload16(Ag + (size_t)r0 * K + tc, &lds[slot][(r0 << 6) + sbase]);
    gload16(Ag + (size_t)r1 * K + tc, &lds[slot][(r1 << 6) + sbase]);
  };
  auto stB = [&](int slot, int tc, int r0, int r1) {
    gload16(Bg + (size_t)r0 * K + tc, &lds[slot][(r0 << 6) + sbase]);
    gload16(Bg + (size_t)r1 * K + tc, &lds[slot][(r1 << 6) + sbase]);
  };

  stB(2, 0, 0, 64); stB(2, 0, 128, 192);
  stA(0, 0, 0, 128); stA(0, 0, 64, 192);

  short8 af[4], bf[4];
  const int NT = K >> 6;
#pragma unroll 2
  for (int t = 0; t < NT; ++t) {
    const int p = t & 1, q = p ^ 1;
    const int tc = ((t + 1) & (NT - 1)) << 6;

    wait_vm2();
    __builtin_amdgcn_s_barrier();
#pragma unroll
    for (int i = 0; i < 4; ++i) af[i] = *(const short8*)&lds[p][ar + (i << 10) + o0];
#pragma unroll
    for (int n = 0; n < 4; ++n) bf[n] = *(const short8*)&lds[2 + p][br + (n << 10) + o0];
    stB(2 + q, tc, 0, 64);
    __builtin_amdgcn_s_barrier();
    wait_lg0();
    __builtin_amdgcn_s_setprio(1);
#pragma unroll
    for (int i = 0; i < 4; ++i)
#pragma unroll
      for (int n = 0; n < 4; ++n)
        acc[i][n] = __builtin_amdgcn_mfma_f32_16x16x32_bf16(af[i], bf[n], acc[i][n], 0, 0, 0);
    __builtin_amdgcn_s_setprio(0);

    wait_vm2();
    __builtin_amdgcn_s_barrier();
#pragma unroll
    for (int i = 0; i < 4; ++i) af[i] = *(const short8*)&lds[p][ar + 4096 + (i << 10) + o0];
    stB(2 + q, tc, 128, 192);
    __builtin_amdgcn_s_barrier();
    wait_lg0();
    __builtin_amdgcn_s_setprio(1);
#pragma unroll
    for (int i = 0; i < 4; ++i)
#pragma unroll
      for (int n = 0; n < 4; ++n)
        acc[4 + i][n] = __builtin_amdgcn_mfma_f32_16x16x32_bf16(af[i], bf[n], acc[4 + i][n], 0, 0, 0);
    __builtin_amdgcn_s_setprio(0);

    __builtin_amdgcn_s_barrier();
#pragma unroll
    for (int i = 0; i < 4; ++i) af[i] = *(const short8*)&lds[p][ar + (i << 10) + o1];
#pragma unroll
    for (int n = 0; n < 4; ++n) bf[n] = *(const short8*)&lds[2 + p][br + (n << 10) + o1];
    stA(q, tc, 0, 128);
    __builtin_amdgcn_s_barrier();
    wait_lg0();
    __builtin_amdgcn_s_setprio(1);
#pragma unroll
    for (int i = 0; i < 4; ++i)
#pragma unroll
      for (int n = 0; n < 4; ++n)
        acc[i][n] = __builtin_amdgcn_mfma_f32_16x16x32_bf16(af[i], bf[n], acc[i][n], 0, 0, 0);
    __builtin_amdgcn_s_setprio(0);

    __builtin_amdgcn_s_barrier();
#pragma unroll
    for (int i = 0; i < 4; ++i) af[i] = *(const short8*)&lds[p][ar + 4096 + (i << 10) + o1];
    stA(q, tc, 64, 192);
    __builtin_amdgcn_s_barrier();
    wait_lg0();
    __builtin_amdgcn_s_setprio(1);
#pragma unroll
    for (int i = 0; i < 4; ++i)
#pragma unroll
      for (int n = 0; n < 4; ++n)
        acc[4 + i][n] = __builtin_amdgcn_mfma_f32_16x16x32_bf16(af[i], bf[n], acc[4 + i][n], 0, 0, 0);
    __builtin_amdgcn_s_setprio(0);
  }
  wait_vm0();

  const int orow = (lane >> 4) << 2;
  const int ocol = lane & 15;
#pragma unroll
  for (int mi = 0; mi < 8; ++mi)
#pragma unroll
    for (int ni = 0; ni < 4; ++ni) {
      f32x4 v = acc[mi][ni];
      const int row0 = (wm << 7) + mi * 16 + orow;
      const int col = bn + (wn << 6) + ni * 16 + ocol;
      if (MODE == 2) {
        u16* C = (u16*)Cout;
        size_t base = (size_t)(bm >> 11) * ((size_t)T_DIM * C_DIM) +
                      (size_t)col * T_DIM + (size_t)((bm & 2047) + row0);
        u16x4 o;
        o[0] = f2bf(v[0]); o[1] = f2bf(v[1]); o[2] = f2bf(v[2]); o[3] = f2bf(v[3]);
        *(u16x4*)&C[base] = o;
      } else {
        size_t base = (size_t)(bm + row0) * N + col;
        if (MODE == 1) {
          float* C = (float*)Cout;
#pragma unroll
          for (int r = 0; r < 4; ++r) C[base + (size_t)r * N] = v[r];
        } else {
          u16* C = (u16*)Cout;
#pragma unroll
          for (int r = 0; r < 4; ++r) C[base + (size_t)r * N] = f2bf(v[r]);
        }
      }
    }
}

// ---------------- causal flash attention (swapped-operand, T12-style) ------
// grid (512), 256 threads = 4 waves x 32 q-rows (2 row-groups of 16).
// QK^T computed as mfma(K,Q) -> S^T: lane owns q = lane&15, holds 16 k-vals
// -> softmax reduction = in-lane + 2 shfl_xor. P stored [q][k] (ds_write_b64).
// PV computed as mfma(V^T,P) -> O^T: lane's output q = lane&15 matches stats;
// rescale shuffle-free; Y written as u16x4 rows.
__global__ __launch_bounds__(256, 2)
void attn_kernel(const u16* __restrict__ Qg, const u16* __restrict__ Kg,
                 const u16* __restrict__ VtG, u16* __restrict__ Y) {
  __shared__ __align__(16) u16 Klds[64][136];
  __shared__ __align__(16) u16 Vlds[128][72];
  __shared__ __align__(16) u16 Plds[4][32][72];
  const int f = blockIdx.x;
  const int pair = (f >> 3) & 7;
  const int bh = (f & 7) | ((f >> 6) << 3);
  const int b = bh >> 4, h = bh & 15;
  const size_t qkbase = (size_t)b * T_DIM * C_DIM + (size_t)h * HD;
  const size_t vtbase = (size_t)b * T_DIM * C_DIM + (size_t)h * HD * T_DIM;
  const int tid = threadIdx.x, wid = tid >> 6, lane = tid & 63;
  const int l15 = lane & 15, g = lane >> 4;
  const float scale2 = 0.08838834764831845f * 1.4426950408889634f;  // scale*log2(e)

  const int kr = tid >> 4, kc = (tid & 15) * 8;   // K rows kr+16j
  const int vr = tid >> 3, vc = (tid & 7) * 8;    // V rows vr+32j
  const u16* Kgp = Kg + qkbase + (size_t)kr * C_DIM + kc;
  const u16* Vgp = VtG + vtbase + (size_t)vr * T_DIM + vc;

  auto process = [&](int qb) {
    const int rlo = qb + wid * 32;
    short8 qf[2][4];
#pragma unroll
    for (int rg = 0; rg < 2; ++rg) {
      const u16* qp = Qg + qkbase + (size_t)(rlo + rg * 16 + l15) * C_DIM + g * 8;
#pragma unroll
      for (int dc = 0; dc < 4; ++dc) qf[rg][dc] = *(const short8*)(qp + dc * 32);
    }
    f32x4 zero4 = {0.f, 0.f, 0.f, 0.f};
    f32x4 ao[2][8];
#pragma unroll
    for (int rg = 0; rg < 2; ++rg)
#pragma unroll
      for (int i = 0; i < 8; ++i) ao[rg][i] = zero4;
    float m_run[2] = {-1e30f, -1e30f};
    float l_run[2] = {0.f, 0.f};
    const int nt = (qb >> 6) + 2;

    ushort8 kN[4], vN[4];
#pragma unroll
    for (int j = 0; j < 4; ++j) {
      kN[j] = *(const ushort8*)(Kgp + (size_t)(16 * j) * C_DIM);
      vN[j] = *(const ushort8*)(Vgp + (size_t)(32 * j) * T_DIM);
    }

    for (int t = 0; t < nt; ++t) {
      const int kb = t * 64;
      __syncthreads();   // LDS free
#pragma unroll
      for (int j = 0; j < 4; ++j) {
        *(ushort8*)&Klds[kr + 16 * j][kc] = kN[j];
        *(ushort8*)&Vlds[vr + 32 * j][vc] = vN[j];
      }
      __syncthreads();   // LDS ready
      if (t + 1 < nt) {  // async-STAGE: next tile under current compute
        const int nkb = kb + 64;
#pragma unroll
        for (int j = 0; j < 4; ++j) {
          kN[j] = *(const ushort8*)(Kgp + (size_t)(nkb + 16 * j) * C_DIM);
          vN[j] = *(const ushort8*)(Vgp + (size_t)(32 * j) * T_DIM + nkb);
        }
      }

      if (kb <= rlo + 31) {
        // S^T = K Q^T : st[rg][jt], lane: q = rlo+rg*16+l15, k = kb+jt*16+g*4+r
        f32x4 st[2][4];
        __builtin_amdgcn_s_setprio(1);
#pragma unroll
        for (int jt = 0; jt < 4; ++jt) {
          short8 kf[4];
#pragma unroll
          for (int dc = 0; dc < 4; ++dc)
            kf[dc] = *(const short8*)&Klds[jt * 16 + l15][dc * 32 + g * 8];
#pragma unroll
          for (int rg = 0; rg < 2; ++rg) {
            f32x4 a = zero4;
#pragma unroll
            for (int dc = 0; dc < 4; ++dc)
              a = __builtin_amdgcn_mfma_f32_16x16x32_bf16(kf[dc], qf[rg][dc], a, 0, 0, 0);
            st[rg][jt] = a;
          }
        }
        __builtin_amdgcn_s_setprio(0);

#pragma unroll
        for (int rg = 0; rg < 2; ++rg) {
          const int qa = rlo + rg * 16 + l15;     // this lane's q row
          const bool domask = (kb + 63) > (rlo + rg * 16);
          // scale + causal mask
#pragma unroll
          for (int jt = 0; jt < 4; ++jt) {
            const int k0 = kb + jt * 16 + g * 4;
#pragma unroll
            for (int r = 0; r < 4; ++r) {
              float sv = st[rg][jt][r] * scale2;
              if (domask && (k0 + r > qa)) sv = -1e30f;
              st[rg][jt][r] = sv;
            }
          }
          // row max: in-lane 16 + 2 shfl
          float mx = st[rg][0][0];
#pragma unroll
          for (int jt = 0; jt < 4; ++jt)
#pragma unroll
            for (int r = 0; r < 4; ++r) mx = fmaxf(mx, st[rg][jt][r]);
          mx = fmaxf(mx, __shfl_xor(mx, 16, 64));
          mx = fmaxf(mx, __shfl_xor(mx, 32, 64));

          // defer-max rescale
          if (__any(mx > m_run[rg] + 8.0f)) {
            float mn = fmaxf(m_run[rg], mx);
            float corr = __builtin_amdgcn_exp2f(m_run[rg] - mn);
            m_run[rg] = mn;
#pragma unroll
            for (int dc = 0; dc < 8; ++dc)
#pragma unroll
              for (int r = 0; r < 4; ++r) ao[rg][dc][r] *= corr;
            l_run[rg] *= corr;
          }

          // P = exp2(S - m), sum, pack to LDS [q][k]
          float sm = 0.f;
#pragma unroll
          for (int jt = 0; jt < 4; ++jt) {
            u16x4 o;
#pragma unroll
            for (int r = 0; r < 4; ++r) {
              float p = __builtin_amdgcn_exp2f(st[rg][jt][r] - m_run[rg]);
              sm += p;
              o[r] = f2bf(p);
            }
            *(u16x4*)&Plds[wid][rg * 16 + l15][jt * 16 + g * 4] = o;
          }
          sm += __shfl_xor(sm, 16, 64);
          sm += __shfl_xor(sm, 32, 64);
          l_run[rg] += sm;
        }

        // O^T += V^T P^T : ao[rg][dc], lane: q = l15, d = dc*16+g*4+r
        short8 pf[2][2];
#pragma unroll
        for (int rg = 0; rg < 2; ++rg)
#pragma unroll
          for (int k2 = 0; k2 < 2; ++k2)
            pf[rg][k2] = *(const short8*)&Plds[wid][rg * 16 + l15][k2 * 32 + g * 8];
        __builtin_amdgcn_s_setprio(1);
#pragma unroll
        for (int dc = 0; dc < 8; ++dc) {
#pragma unroll
          for (int k2 = 0; k2 < 2; ++k2) {
            short8 vf = *(const short8*)&Vlds[dc * 16 + l15][k2 * 32 + g * 8];
            ao[0][dc] = __builtin_amdgcn_mfma_f32_16x16x32_bf16(vf, pf[0][k2], ao[0][dc], 0, 0, 0);
            ao[1][dc] = __builtin_amdgcn_mfma_f32_16x16x32_bf16(vf, pf[1][k2], ao[1][dc], 0, 0, 0);
          }
        }
        __builtin_amdgcn_s_setprio(0);
      }
    }

    // write Y: lane's q = l15; d = dc*16 + g*4 + r (u16x4 per dc)
#pragma unroll
    for (int rg = 0; rg < 2; ++rg) {
      float rcp = 1.0f / l_run[rg];
      u16* yp = Y + qkbase + (size_t)(rlo + rg * 16 + l15) * C_DIM + g * 4;
#pragma unroll
      for (int dc = 0; dc < 8; ++dc) {
        u16x4 o;
#pragma unroll
        for (int r = 0; r < 4; ++r) o[r] = f2bf(ao[rg][dc][r] * rcp);
        *(u16x4*)&yp[dc * 16] = o;
      }
    }
  };

  process(pair * 128);
  process((15 - pair) * 128);
}

extern "C" void kernel_launch(void* const* d_in, const int* in_sizes, int n_in,
                              void* d_out, int out_size, void* d_ws, size_t ws_size,
                              hipStream_t stream) {
  const float* x  = (const float*)d_in[0];
  const float* Wq = (const float*)d_in[1];
  const float* Wk = (const float*)d_in[2];
  const float* Wv = (const float*)d_in[3];
  const float* Wo = (const float*)d_in[4];
  float* out = (float*)d_out;

  const size_t SZX = (size_t)8192 * 2048;
  const size_t SZW = (size_t)2048 * 2048;
  u16* xb  = (u16*)d_ws;
  u16* Wqb = xb + SZX;
  u16* Wkb = Wqb + SZW;
  u16* Wvb = Wkb + SZW;
  u16* Wob = Wvb + SZW;
  u16* Qb  = Wob + SZW;   // Q, overwritten in place by attention output Y
  u16* Kb  = Qb + SZX;
  u16* Vb  = Kb + SZX;    // V^T in [b][n][t] layout

  cast_bf16_kernel<<<(int)(SZX / 2048), 256, 0, stream>>>(x,  xb,  (int)SZX);
  cast_bf16_kernel<<<(int)(SZW / 2048), 256, 0, stream>>>(Wq, Wqb, (int)SZW);
  cast_bf16_kernel<<<(int)(SZW / 2048), 256, 0, stream>>>(Wk, Wkb, (int)SZW);
  cast_bf16_kernel<<<(int)(SZW / 2048), 256, 0, stream>>>(Wv, Wvb, (int)SZW);
  cast_bf16_kernel<<<(int)(SZW / 2048), 256, 0, stream>>>(Wo, Wob, (int)SZW);

  gemm256<0><<<256, 512, 0, stream>>>(xb, Wqb, Qb, 8192, 2048, 2048);
  gemm256<0><<<256, 512, 0, stream>>>(xb, Wkb, Kb, 8192, 2048, 2048);
  gemm256<2><<<256, 512, 0, stream>>>(xb, Wvb, Vb, 8192, 2048, 2048);  // V^T out

  attn_kernel<<<512, 256, 0, stream>>>(Qb, Kb, Vb, Qb);

  gemm256<1><<<256, 512, 0, stream>>>(Qb, Wob, out, 8192, 2048, 2048);
}

// Round 8
// 373.889 us; speedup vs baseline: 3.0319x; 1.0278x over previous
//
#include <hip/hip_runtime.h>
#include <stdint.h>

#define B_DIM 4
#define T_DIM 2048
#define C_DIM 2048
#define NH 16
#define HD 128

typedef unsigned short u16;
typedef __attribute__((ext_vector_type(8))) short short8;
typedef __attribute__((ext_vector_type(8))) u16 ushort8;
typedef __attribute__((ext_vector_type(4))) u16 u16x4;
typedef __attribute__((ext_vector_type(2))) uint32_t u32x2;
typedef __attribute__((ext_vector_type(4))) float f32x4;

// scale / sqrt(128) * log2(e), folded into Q-projection epilogue (MODE 3)
#define QSCALE (0.08838834764831845f * 1.4426950408889634f)

__device__ __forceinline__ u16 f2bf(float f) {
  uint32_t u = __builtin_bit_cast(uint32_t, f);
  u = (u + 0x7FFFu + ((u >> 16) & 1u)) >> 16;
  return (u16)u;
}

__device__ __forceinline__ uint32_t cvtpk(float lo, float hi) {
  uint32_t r;
  asm("v_cvt_pk_bf16_f32 %0, %1, %2" : "=v"(r) : "v"(lo), "v"(hi));
  return r;
}

__device__ __forceinline__ void gload16(const void* g, void* l) {
  __builtin_amdgcn_global_load_lds(
      (const __attribute__((address_space(1))) void*)g,
      (__attribute__((address_space(3))) void*)l, 16, 0, 0);
}

__device__ __forceinline__ void wait_vm2() { asm volatile("s_waitcnt vmcnt(2)" ::: "memory"); }
__device__ __forceinline__ void wait_vm0() { asm volatile("s_waitcnt vmcnt(0)" ::: "memory"); }
__device__ __forceinline__ void wait_lg0() {
  asm volatile("s_waitcnt lgkmcnt(0)" ::: "memory");
  __builtin_amdgcn_sched_barrier(0);
}

// ---------------- cast f32 -> bf16, 8 elems/thread ----------------
__global__ void cast_bf16_kernel(const float* __restrict__ src, u16* __restrict__ dst, int n) {
  int i = (blockIdx.x * 256 + threadIdx.x) * 8;
  if (i >= n) return;
  f32x4 a = *(const f32x4*)(src + i);
  f32x4 b = *(const f32x4*)(src + i + 4);
  ushort8 o;
  o[0] = f2bf(a[0]); o[1] = f2bf(a[1]); o[2] = f2bf(a[2]); o[3] = f2bf(a[3]);
  o[4] = f2bf(b[0]); o[5] = f2bf(b[1]); o[6] = f2bf(b[2]); o[7] = f2bf(b[3]);
  *(ushort8*)(dst + i) = o;
}

// fused 4-weight cast: 2048 blocks per 4M-element array
__global__ void cast_w4_kernel(const float* __restrict__ s0, const float* __restrict__ s1,
                               const float* __restrict__ s2, const float* __restrict__ s3,
                               u16* __restrict__ d0, u16* __restrict__ d1,
                               u16* __restrict__ d2, u16* __restrict__ d3) {
  const int a = blockIdx.x >> 11;
  const float* s = a == 0 ? s0 : a == 1 ? s1 : a == 2 ? s2 : s3;
  u16* d = a == 0 ? d0 : a == 1 ? d1 : a == 2 ? d2 : d3;
  int i = ((blockIdx.x & 2047) * 256 + threadIdx.x) * 8;
  f32x4 x = *(const f32x4*)(s + i);
  f32x4 y = *(const f32x4*)(s + i + 4);
  ushort8 o;
  o[0] = f2bf(x[0]); o[1] = f2bf(x[1]); o[2] = f2bf(x[2]); o[3] = f2bf(x[3]);
  o[4] = f2bf(y[0]); o[5] = f2bf(y[1]); o[6] = f2bf(y[2]); o[7] = f2bf(y[3]);
  *(ushort8*)(d + i) = o;
}

// ---------------- NT GEMM, 256x256 tile, BK=64, 8 waves, 4-phase/K-tile ----
// MODE 0: bf16 out. MODE 1: f32 out. MODE 2: bf16 V^T out. MODE 3: bf16*QSCALE.
template<int MODE>
__global__ __launch_bounds__(512, 2)
void gemm256(const u16* __restrict__ A, const u16* __restrict__ Bw,
             void* __restrict__ Cout, int M, int N, int K) {
  __shared__ __align__(16) u16 lds[4][16384];
  const int nbn = N >> 8;
  const int cpx = gridDim.x >> 3;
  const int swz = (blockIdx.x & 7) * cpx + (blockIdx.x >> 3);
  const int bm = (swz / nbn) << 8;
  const int bn = (swz % nbn) << 8;
  const int tid = threadIdx.x, wid = tid >> 6, lane = tid & 63;
  const int wm = wid >> 2, wn = wid & 3;

  const int srow = (wid << 3) + (lane >> 3);
  const int scol = ((lane & 7) ^ (lane >> 3)) << 3;
  const u16* Ag = A + (size_t)(bm + srow) * K + scol;
  const u16* Bg = Bw + (size_t)(bn + srow) * K + scol;
  const int sbase = wid << 9;

  const int l15 = lane & 15;
  const int o0 = ((lane >> 4) ^ (lane & 7)) << 3;
  const int o1 = ((4 | (lane >> 4)) ^ (lane & 7)) << 3;
  const int ar = ((wm << 7) + l15) << 6;
  const int br = ((wn << 6) + l15) << 6;

  f32x4 acc[8][4];
  f32x4 zero4 = {0.f, 0.f, 0.f, 0.f};
#pragma unroll
  for (int i = 0; i < 8; ++i)
#pragma unroll
    for (int n = 0; n < 4; ++n) acc[i][n] = zero4;

  auto stA = [&](int slot, int tc, int r0, int r1) {
    gload16(Ag + (size_t)r0 * K + tc, &lds[slot][(r0 << 6) + sbase]);
    gload16(Ag + (size_t)r1 * K + tc, &lds[slot][(r1 << 6) + sbase]);
  };
  auto stB = [&](int slot, int tc, int r0, int r1) {
    gload16(Bg + (size_t)r0 * K + tc, &lds[slot][(r0 << 6) + sbase]);
    gload16(Bg + (size_t)r1 * K + tc, &lds[slot][(r1 << 6) + sbase]);
  };

  stB(2, 0, 0, 64); stB(2, 0, 128, 192);
  stA(0, 0, 0, 128); stA(0, 0, 64, 192);

  short8 af[4], bf[4];
  const int NT = K >> 6;
#pragma unroll 2
  for (int t = 0; t < NT; ++t) {
    const int p = t & 1, q = p ^ 1;
    const int tc = ((t + 1) & (NT - 1)) << 6;

    wait_vm2();
    __builtin_amdgcn_s_barrier();
#pragma unroll
    for (int i = 0; i < 4; ++i) af[i] = *(const short8*)&lds[p][ar + (i << 10) + o0];
#pragma unroll
    for (int n = 0; n < 4; ++n) bf[n] = *(const short8*)&lds[2 + p][br + (n << 10) + o0];
    stB(2 + q, tc, 0, 64);
    __builtin_amdgcn_s_barrier();
    wait_lg0();
    __builtin_amdgcn_s_setprio(1);
#pragma unroll
    for (int i = 0; i < 4; ++i)
#pragma unroll
      for (int n = 0; n < 4; ++n)
        acc[i][n] = __builtin_amdgcn_mfma_f32_16x16x32_bf16(af[i], bf[n], acc[i][n], 0, 0, 0);
    __builtin_amdgcn_s_setprio(0);

    wait_vm2();
    __builtin_amdgcn_s_barrier();
#pragma unroll
    for (int i = 0; i < 4; ++i) af[i] = *(const short8*)&lds[p][ar + 4096 + (i << 10) + o0];
    stB(2 + q, tc, 128, 192);
    __builtin_amdgcn_s_barrier();
    wait_lg0();
    __builtin_amdgcn_s_setprio(1);
#pragma unroll
    for (int i = 0; i < 4; ++i)
#pragma unroll
      for (int n = 0; n < 4; ++n)
        acc[4 + i][n] = __builtin_amdgcn_mfma_f32_16x16x32_bf16(af[i], bf[n], acc[4 + i][n], 0, 0, 0);
    __builtin_amdgcn_s_setprio(0);

    __builtin_amdgcn_s_barrier();
#pragma unroll
    for (int i = 0; i < 4; ++i) af[i] = *(const short8*)&lds[p][ar + (i << 10) + o1];
#pragma unroll
    for (int n = 0; n < 4; ++n) bf[n] = *(const short8*)&lds[2 + p][br + (n << 10) + o1];
    stA(q, tc, 0, 128);
    __builtin_amdgcn_s_barrier();
    wait_lg0();
    __builtin_amdgcn_s_setprio(1);
#pragma unroll
    for (int i = 0; i < 4; ++i)
#pragma unroll
      for (int n = 0; n < 4; ++n)
        acc[i][n] = __builtin_amdgcn_mfma_f32_16x16x32_bf16(af[i], bf[n], acc[i][n], 0, 0, 0);
    __builtin_amdgcn_s_setprio(0);

    __builtin_amdgcn_s_barrier();
#pragma unroll
    for (int i = 0; i < 4; ++i) af[i] = *(const short8*)&lds[p][ar + 4096 + (i << 10) + o1];
    stA(q, tc, 64, 192);
    __builtin_amdgcn_s_barrier();
    wait_lg0();
    __builtin_amdgcn_s_setprio(1);
#pragma unroll
    for (int i = 0; i < 4; ++i)
#pragma unroll
      for (int n = 0; n < 4; ++n)
        acc[4 + i][n] = __builtin_amdgcn_mfma_f32_16x16x32_bf16(af[i], bf[n], acc[4 + i][n], 0, 0, 0);
    __builtin_amdgcn_s_setprio(0);
  }
  wait_vm0();

  const int orow = (lane >> 4) << 2;
  const int ocol = lane & 15;
  const float sc = (MODE == 3) ? QSCALE : 1.0f;
#pragma unroll
  for (int mi = 0; mi < 8; ++mi)
#pragma unroll
    for (int ni = 0; ni < 4; ++ni) {
      f32x4 v = acc[mi][ni];
      const int row0 = (wm << 7) + mi * 16 + orow;
      const int col = bn + (wn << 6) + ni * 16 + ocol;
      if (MODE == 2) {
        u16* C = (u16*)Cout;
        size_t base = (size_t)(bm >> 11) * ((size_t)T_DIM * C_DIM) +
                      (size_t)col * T_DIM + (size_t)((bm & 2047) + row0);
        u16x4 o;
        o[0] = f2bf(v[0]); o[1] = f2bf(v[1]); o[2] = f2bf(v[2]); o[3] = f2bf(v[3]);
        *(u16x4*)&C[base] = o;
      } else {
        size_t base = (size_t)(bm + row0) * N + col;
        if (MODE == 1) {
          float* C = (float*)Cout;
#pragma unroll
          for (int r = 0; r < 4; ++r) C[base + (size_t)r * N] = v[r];
        } else {
          u16* C = (u16*)Cout;
#pragma unroll
          for (int r = 0; r < 4; ++r) C[base + (size_t)r * N] = f2bf(v[r] * sc);
        }
      }
    }
}

// ---------------- causal flash attention (swapped-operand, 8 waves) --------
// grid (512), 512 threads = 8 waves x 16 q-rows = 128 rows/block; pairs
// (p, 15-p) -> 34 KV tiles, balanced. 2 blocks/CU = 16 waves/CU.
// Q pre-scaled by scale*log2e in the Q-GEMM. Lane owns q = lane&15 throughout:
// softmax in-lane + 2 shfl (max only); l kept as per-lane partial, reduced once.
__global__ __launch_bounds__(512, 4)
void attn_kernel(const u16* __restrict__ Qg, const u16* __restrict__ Kg,
                 const u16* __restrict__ VtG, u16* __restrict__ Y) {
  __shared__ __align__(16) u16 Klds[64][136];
  __shared__ __align__(16) u16 Vlds[128][72];
  __shared__ __align__(16) u16 Plds[8][16][72];
  const int f = blockIdx.x;
  const int pair = (f >> 3) & 7;
  const int bh = (f & 7) | ((f >> 6) << 3);
  const int b = bh >> 4, h = bh & 15;
  const size_t qkbase = (size_t)b * T_DIM * C_DIM + (size_t)h * HD;
  const size_t vtbase = (size_t)b * T_DIM * C_DIM + (size_t)h * HD * T_DIM;
  const int tid = threadIdx.x, wid = tid >> 6, lane = tid & 63;
  const int l15 = lane & 15, g = lane >> 4;

  const int kr = tid >> 4, kc = (tid & 15) * 8;   // K rows kr, kr+32
  const int vr = tid >> 3, vc = (tid & 7) * 8;    // V rows vr, vr+64
  const u16* Kgp = Kg + qkbase + (size_t)kr * C_DIM + kc;
  const u16* Vgp = VtG + vtbase + (size_t)vr * T_DIM + vc;

  auto process = [&](int qb) {
    const int rlo = qb + wid * 16;
    short8 qf[4];
    {
      const u16* qp = Qg + qkbase + (size_t)(rlo + l15) * C_DIM + g * 8;
#pragma unroll
      for (int dc = 0; dc < 4; ++dc) qf[dc] = *(const short8*)(qp + dc * 32);
    }
    f32x4 zero4 = {0.f, 0.f, 0.f, 0.f};
    f32x4 ao[8];
#pragma unroll
    for (int i = 0; i < 8; ++i) ao[i] = zero4;
    float m_run = -1e30f;
    float l_lane = 0.f;           // per-lane partial row sum (lane's 16 cols)
    const int nt = (qb >> 6) + 2;

    ushort8 kN[2], vN[2];
    kN[0] = *(const ushort8*)(Kgp);
    kN[1] = *(const ushort8*)(Kgp + 32 * (size_t)C_DIM);
    vN[0] = *(const ushort8*)(Vgp);
    vN[1] = *(const ushort8*)(Vgp + 64 * (size_t)T_DIM);

    for (int t = 0; t < nt; ++t) {
      const int kb = t * 64;
      __syncthreads();   // LDS free
      *(ushort8*)&Klds[kr][kc]      = kN[0];
      *(ushort8*)&Klds[kr + 32][kc] = kN[1];
      *(ushort8*)&Vlds[vr][vc]      = vN[0];
      *(ushort8*)&Vlds[vr + 64][vc] = vN[1];
      __syncthreads();   // LDS ready
      if (t + 1 < nt) {  // async-STAGE next tile under current compute
        const int nkb = kb + 64;
        kN[0] = *(const ushort8*)(Kgp + (size_t)nkb * C_DIM);
        kN[1] = *(const ushort8*)(Kgp + (size_t)(nkb + 32) * C_DIM);
        vN[0] = *(const ushort8*)(Vgp + nkb);
        vN[1] = *(const ushort8*)(Vgp + 64 * (size_t)T_DIM + nkb);
      }

      if (kb <= rlo + 15) {
        // S^T: lane q = rlo+l15, k = kb + jt*16 + g*4 + r (pre-scaled, log2)
        f32x4 st[4];
        __builtin_amdgcn_s_setprio(1);
#pragma unroll
        for (int jt = 0; jt < 4; ++jt) {
          f32x4 a = zero4;
#pragma unroll
          for (int dc = 0; dc < 4; ++dc) {
            short8 kf = *(const short8*)&Klds[jt * 16 + l15][dc * 32 + g * 8];
            a = __builtin_amdgcn_mfma_f32_16x16x32_bf16(kf, qf[dc], a, 0, 0, 0);
          }
          st[jt] = a;
        }
        __builtin_amdgcn_s_setprio(0);

        // causal mask: only diagonal-overlapping tiles (uniform branch)
        if (kb + 63 > rlo) {
          const int qa = rlo + l15;
#pragma unroll
          for (int jt = 0; jt < 4; ++jt) {
            const int k0 = kb + jt * 16 + g * 4;
#pragma unroll
            for (int r = 0; r < 4; ++r)
              if (k0 + r > qa) st[jt][r] = -1e30f;
          }
        }

        // row max: in-lane 16 + 2 shfl
        float mx = st[0][0];
#pragma unroll
        for (int jt = 0; jt < 4; ++jt)
#pragma unroll
          for (int r = 0; r < 4; ++r) mx = fmaxf(mx, st[jt][r]);
        mx = fmaxf(mx, __shfl_xor(mx, 16, 64));
        mx = fmaxf(mx, __shfl_xor(mx, 32, 64));

        // defer-max rescale
        if (__any(mx > m_run + 8.0f)) {
          float mn = fmaxf(m_run, mx);
          float corr = __builtin_amdgcn_exp2f(m_run - mn);
          m_run = mn;
#pragma unroll
          for (int dc = 0; dc < 8; ++dc)
#pragma unroll
            for (int r = 0; r < 4; ++r) ao[dc][r] *= corr;
          l_lane *= corr;
        }

        // P = exp2(S - m), per-lane sum, pack pairs to LDS [q][k]
#pragma unroll
        for (int jt = 0; jt < 4; ++jt) {
          float p0 = __builtin_amdgcn_exp2f(st[jt][0] - m_run);
          float p1 = __builtin_amdgcn_exp2f(st[jt][1] - m_run);
          float p2 = __builtin_amdgcn_exp2f(st[jt][2] - m_run);
          float p3 = __builtin_amdgcn_exp2f(st[jt][3] - m_run);
          l_lane += (p0 + p1) + (p2 + p3);
          u32x2 w;
          w[0] = cvtpk(p0, p1);
          w[1] = cvtpk(p2, p3);
          *(u32x2*)&Plds[wid][l15][jt * 16 + g * 4] = w;
        }

        // O^T += V^T P^T : lane q = l15, d = dc*16 + g*4 + r
        short8 pf[2];
#pragma unroll
        for (int k2 = 0; k2 < 2; ++k2)
          pf[k2] = *(const short8*)&Plds[wid][l15][k2 * 32 + g * 8];
        __builtin_amdgcn_s_setprio(1);
#pragma unroll
        for (int dc = 0; dc < 8; ++dc) {
#pragma unroll
          for (int k2 = 0; k2 < 2; ++k2) {
            short8 vf = *(const short8*)&Vlds[dc * 16 + l15][k2 * 32 + g * 8];
            ao[dc] = __builtin_amdgcn_mfma_f32_16x16x32_bf16(vf, pf[k2], ao[dc], 0, 0, 0);
          }
        }
        __builtin_amdgcn_s_setprio(0);
      }
    }

    // final l reduce (2 shfl) + normalize + write Y
    float l = l_lane;
    l += __shfl_xor(l, 16, 64);
    l += __shfl_xor(l, 32, 64);
    const float rcp = 1.0f / l;
    u16* yp = Y + qkbase + (size_t)(rlo + l15) * C_DIM + g * 4;
#pragma unroll
    for (int dc = 0; dc < 8; ++dc) {
      u32x2 w;
      w[0] = cvtpk(ao[dc][0] * rcp, ao[dc][1] * rcp);
      w[1] = cvtpk(ao[dc][2] * rcp, ao[dc][3] * rcp);
      *(u32x2*)&yp[dc * 16] = w;
    }
  };

  process(pair * 128);
  process((15 - pair) * 128);
}

extern "C" void kernel_launch(void* const* d_in, const int* in_sizes, int n_in,
                              void* d_out, int out_size, void* d_ws, size_t ws_size,
                              hipStream_t stream) {
  const float* x  = (const float*)d_in[0];
  const float* Wq = (const float*)d_in[1];
  const float* Wk = (const float*)d_in[2];
  const float* Wv = (const float*)d_in[3];
  const float* Wo = (const float*)d_in[4];
  float* out = (float*)d_out;

  const size_t SZX = (size_t)8192 * 2048;
  const size_t SZW = (size_t)2048 * 2048;
  u16* xb  = (u16*)d_ws;
  u16* Wqb = xb + SZX;
  u16* Wkb = Wqb + SZW;
  u16* Wvb = Wkb + SZW;
  u16* Wob = Wvb + SZW;
  u16* Qb  = Wob + SZW;   // Q (pre-scaled), overwritten in place by attn Y
  u16* Kb  = Qb + SZX;
  u16* Vb  = Kb + SZX;    // V^T in [b][n][t] layout

  cast_bf16_kernel<<<(int)(SZX / 2048), 256, 0, stream>>>(x, xb, (int)SZX);
  cast_w4_kernel<<<8192, 256, 0, stream>>>(Wq, Wk, Wv, Wo, Wqb, Wkb, Wvb, Wob);

  gemm256<3><<<256, 512, 0, stream>>>(xb, Wqb, Qb, 8192, 2048, 2048);  // Q*scale
  gemm256<0><<<256, 512, 0, stream>>>(xb, Wkb, Kb, 8192, 2048, 2048);
  gemm256<2><<<256, 512, 0, stream>>>(xb, Wvb, Vb, 8192, 2048, 2048);  // V^T out

  attn_kernel<<<512, 512, 0, stream>>>(Qb, Kb, Vb, Qb);

  gemm256<1><<<256, 512, 0, stream>>>(Qb, Wob, out, 8192, 2048, 2048);
}